// Round 1
// baseline (4403.820 us; speedup 1.0000x reference)
//
#include <hip/hip_runtime.h>
#include <math.h>

#define B_ 8192
#define E_ 100
#define D_ 300
#define P_ 100
#define H_ 20
#define F_ 202   // 2P+2

// ---------------------------------------------------------------------------
// Kernel 1: gating softmax  w[b,e] = softmax_e( (x+y)[b,:] @ W_all[:,e] )
// one block (128 thr) per batch row
// ---------------------------------------------------------------------------
__global__ __launch_bounds__(128) void gate_kernel(
    const float* __restrict__ x, const float* __restrict__ y,
    const float* __restrict__ wall, float* __restrict__ wgate)
{
    __shared__ float s[D_];
    __shared__ float zv[128];
    __shared__ float red[128];
    const int b = blockIdx.x;
    const int tid = threadIdx.x;

    for (int d = tid; d < D_; d += 128)
        s[d] = x[(size_t)b * D_ + d] + y[(size_t)b * D_ + d];
    __syncthreads();

    float acc = 0.f;
    if (tid < E_) {
        for (int d = 0; d < D_; ++d)
            acc += s[d] * wall[(size_t)d * E_ + tid];
    }
    zv[tid] = (tid < E_) ? acc : -INFINITY;
    red[tid] = zv[tid];
    __syncthreads();

    for (int st = 64; st > 0; st >>= 1) {
        if (tid < st) red[tid] = fmaxf(red[tid], red[tid + st]);
        __syncthreads();
    }
    const float m = red[0];
    __syncthreads();

    const float ev = (tid < E_) ? expf(zv[tid] - m) : 0.f;
    red[tid] = ev;
    __syncthreads();
    for (int st = 64; st > 0; st >>= 1) {
        if (tid < st) red[tid] += red[tid + st];
        __syncthreads();
    }
    const float sum = red[0];
    if (tid < E_) wgate[(size_t)b * E_ + tid] = ev / sum;
}

// ---------------------------------------------------------------------------
// Kernel 2: fused main.  grid = (B/32, E), block = 256 threads.
// Per block: 32 batch rows x 1 expert.
//   phase A: xp = x@W1[e]+b1, yp = y@W1[e]+b1  (register-tiled fp32 GEMM)
//   phase B: cos similarity, feat assembly in LDS
//   phase C: hidden layer (202->20), out layer (20->1), out[b] += w[b,e]*d
// ---------------------------------------------------------------------------
#define BT 32          // batch rows per block
#define DK 25          // D-chunk depth (300 = 12*25)

__global__ __launch_bounds__(256) void moe_fused_kernel(
    const float* __restrict__ x, const float* __restrict__ y,
    const float* __restrict__ tag,
    const float* __restrict__ w1,     // [E][D][P]
    const float* __restrict__ b1,     // [E][P]
    const float* __restrict__ wh,     // [E][202][20]
    const float* __restrict__ hb,     // [E][20]
    const float* __restrict__ wo,     // [E][20]
    const float* __restrict__ ob,     // [E]
    const float* __restrict__ wgate,  // [B][E]
    float* __restrict__ out)          // [B]
{
    // region shA is time-multiplexed: {sx,sy,sw staging} -> {red} -> {swh}
    __shared__ float shA[4164];
    __shared__ float feat[BT][F_ + 2];   // [32][204]
    __shared__ float wrow[BT];
    __shared__ float sd[BT];
    __shared__ float shb[H_];
    __shared__ float swo[H_];

    float (*sx)[26]   = (float (*)[26])shA;            //  832 floats
    float (*sy)[26]   = (float (*)[26])(shA + 832);    //  832 floats
    float (*sw)[P_]   = (float (*)[P_])(shA + 1664);   // 2500 floats

    const int tid = threadIdx.x;
    const int cg  = tid & 31;   // column group (cols cg, cg+32, cg+64, [cg+96])
    const int rg  = tid >> 5;   // row group (rows rg, rg+8, rg+16, rg+24)
    const int b0  = blockIdx.x * BT;
    const int e   = blockIdx.y;

    const float* W1e = w1 + (size_t)e * (D_ * P_);

    float ax[4][4] = {{0.f}}, ay[4][4] = {{0.f}};

    // ---------------- phase A: projection GEMM over D chunks ---------------
    for (int d0 = 0; d0 < D_; d0 += DK) {
        for (int k = tid; k < BT * DK; k += 256) {
            const int rr = k / DK, dd = k - rr * DK;
            sx[rr][dd] = x[(size_t)(b0 + rr) * D_ + d0 + dd];
            sy[rr][dd] = y[(size_t)(b0 + rr) * D_ + d0 + dd];
        }
        for (int k = tid; k < DK * P_; k += 256) {
            const int dd = k / P_, p = k - dd * P_;
            sw[dd][p] = W1e[(size_t)(d0 + dd) * P_ + p];
        }
        __syncthreads();

        #pragma unroll 5
        for (int dd = 0; dd < DK; ++dd) {
            const float wv0 = sw[dd][cg];
            const float wv1 = sw[dd][cg + 32];
            const float wv2 = sw[dd][cg + 64];
            const float wv3 = sw[dd][(cg < 4) ? cg + 96 : 99]; // dummy if cg>=4
            #pragma unroll
            for (int i = 0; i < 4; ++i) {
                const float xv = sx[rg + 8 * i][dd];
                const float yv = sy[rg + 8 * i][dd];
                ax[i][0] += xv * wv0;  ay[i][0] += yv * wv0;
                ax[i][1] += xv * wv1;  ay[i][1] += yv * wv1;
                ax[i][2] += xv * wv2;  ay[i][2] += yv * wv2;
                ax[i][3] += xv * wv3;  ay[i][3] += yv * wv3;
            }
        }
        __syncthreads();
    }

    // ---------------- phase B: bias, feat entries, cos partials ------------
    float pxx[4] = {0.f, 0.f, 0.f, 0.f};
    float pyy[4] = {0.f, 0.f, 0.f, 0.f};
    float pxy[4] = {0.f, 0.f, 0.f, 0.f};

    #pragma unroll
    for (int j = 0; j < 4; ++j) {
        const int c = cg + 32 * j;
        if (c < P_) {
            const float bp = b1[(size_t)e * P_ + c];
            #pragma unroll
            for (int i = 0; i < 4; ++i) {
                const float xv = ax[i][j] + bp;
                const float yv = ay[i][j] + bp;
                const int r = rg + 8 * i;
                feat[r][1 + c]        = xv + yv;
                feat[r][1 + P_ + c]   = fabsf(xv - yv);
                pxx[i] += xv * xv;
                pyy[i] += yv * yv;
                pxy[i] += xv * yv;
            }
        }
    }

    // staging region is dead (loop ended with syncthreads) -> reuse as red
    float* red = shA;   // [3][32][33]
    #pragma unroll
    for (int i = 0; i < 4; ++i) {
        const int r = rg + 8 * i;
        red[0 * 1056 + r * 33 + cg] = pxx[i];
        red[1 * 1056 + r * 33 + cg] = pyy[i];
        red[2 * 1056 + r * 33 + cg] = pxy[i];
    }
    __syncthreads();

    if (tid < 96) {
        const int q = tid >> 5, r = tid & 31;
        float s = 0.f;
        for (int c2 = 0; c2 < 32; ++c2) s += red[q * 1056 + r * 33 + c2];
        red[q * 1056 + r * 33 + 32] = s;
    }
    __syncthreads();

    if (tid < BT) {
        const int r = tid;
        const float sxx = red[0 * 1056 + r * 33 + 32];
        const float syy = red[1 * 1056 + r * 33 + 32];
        const float sxy = red[2 * 1056 + r * 33 + 32];
        const float nx = fmaxf(sqrtf(sxx), 1e-8f);
        const float ny = fmaxf(sqrtf(syy), 1e-8f);
        feat[r][0]      = sxy / (nx * ny);
        feat[r][F_ - 1] = tag[b0 + r];
        wrow[r] = wgate[(size_t)(b0 + r) * E_ + e];
        sd[r]   = ob[e];
    }
    __syncthreads();

    // red is consumed -> reuse shA as swh [202][20]
    float* swh = shA;
    for (int k = tid; k < F_ * H_; k += 256)
        swh[k] = wh[(size_t)e * (F_ * H_) + k];
    if (tid < H_) {
        shb[tid] = hb[(size_t)e * H_ + tid];
        swo[tid] = wo[(size_t)e * H_ + tid];
    }
    __syncthreads();

    // ---------------- phase C: hidden (202->20) + out (20->1) --------------
    if (tid < BT * 5) {          // 160 threads: (row, 4-wide hidden-col group)
        const int r   = tid / 5;
        const int hc0 = (tid - r * 5) * 4;
        float a0 = shb[hc0], a1 = shb[hc0 + 1], a2 = shb[hc0 + 2], a3 = shb[hc0 + 3];
        for (int f = 0; f < F_; ++f) {
            const float fv = feat[r][f];
            const float4 wv = *(const float4*)&swh[f * H_ + hc0];
            a0 += fv * wv.x;  a1 += fv * wv.y;  a2 += fv * wv.z;  a3 += fv * wv.w;
        }
        const float dpart = fmaxf(a0, 0.f) * swo[hc0]
                          + fmaxf(a1, 0.f) * swo[hc0 + 1]
                          + fmaxf(a2, 0.f) * swo[hc0 + 2]
                          + fmaxf(a3, 0.f) * swo[hc0 + 3];
        atomicAdd(&sd[r], dpart);
    }
    __syncthreads();

    if (tid < BT)
        atomicAdd(&out[b0 + tid], wrow[tid] * sd[tid]);
}

// ---------------------------------------------------------------------------
extern "C" void kernel_launch(void* const* d_in, const int* in_sizes, int n_in,
                              void* d_out, int out_size, void* d_ws, size_t ws_size,
                              hipStream_t stream)
{
    const float* x    = (const float*)d_in[0];
    const float* y    = (const float*)d_in[1];
    const float* tag  = (const float*)d_in[2];
    const float* w1   = (const float*)d_in[3];
    const float* b1   = (const float*)d_in[4];
    const float* wh   = (const float*)d_in[5];
    const float* hb   = (const float*)d_in[6];
    const float* wo   = (const float*)d_in[7];
    const float* ob   = (const float*)d_in[8];
    const float* wall = (const float*)d_in[9];

    float* out   = (float*)d_out;
    float* wgate = (float*)d_ws;   // B*E floats = 3.28 MB

    hipMemsetAsync(out, 0, (size_t)B_ * sizeof(float), stream);

    gate_kernel<<<dim3(B_), dim3(128), 0, stream>>>(x, y, wall, wgate);

    moe_fused_kernel<<<dim3(B_ / BT, E_), dim3(256), 0, stream>>>(
        x, y, tag, w1, b1, wh, hb, wo, ob, wgate, out);
}

// Round 4
// 1137.807 us; speedup vs baseline: 3.8704x; 3.8704x over previous
//
#include <hip/hip_runtime.h>
#include <math.h>

#define B_ 8192
#define E_ 100
#define D_ 300
#define P_ 100
#define H_ 20
#define F_ 202   // 2P+2
#define NT 10    // K steps of 32 (300 padded to 320)

typedef __attribute__((ext_vector_type(8))) short bf16x8;
typedef __attribute__((ext_vector_type(4))) _Float16 f16x4;
typedef __attribute__((ext_vector_type(4))) float f32x4;
typedef __attribute__((ext_vector_type(8))) unsigned short us8;

// ---- workspace layout (bytes) ----
// A tiles: [128 rb][10 t][2 part(hi|lo)][4 kg][128 row][8 k] bf16 = 16 KB/tile
// B tiles: [100 e][10 t][2 part(hi|lo)][4 kg][112 p][8 k] bf16  = 14 KB/tile
#define WG_OFF 0                         // wgate [B][E] f32        (3,276,800)
#define AB_OFF 3276800                   // 128*10*8192 halves      (20,971,520)
#define W1_OFF (AB_OFF + 20971520)       // 100*10*7168 halves      (14,336,000)
// total 38,584,320 bytes

__device__ __forceinline__ unsigned short f2bf(float f) {
    unsigned int u = __float_as_uint(f);
    u = (u + 0x7FFF + ((u >> 16) & 1)) >> 16;   // RNE
    return (unsigned short)u;
}
__device__ __forceinline__ float bf2f(unsigned short h) {
    return __uint_as_float(((unsigned int)h) << 16);
}

#define GLOAD16(g, l) \
    __builtin_amdgcn_global_load_lds((const __attribute__((address_space(1))) unsigned int*)(g), \
                                     (__attribute__((address_space(3))) unsigned int*)(l), 16, 0, 0)

// ---------------------------------------------------------------------------
// prep: x,y -> split bf16 A-tiles. tile(rb,t) = [2][4 kg][128 row][8 k]
// rows 0..63 = x rows, 64..127 = y rows. k >= 300 zero-padded.
// ---------------------------------------------------------------------------
__global__ __launch_bounds__(256) void prep_xy(const float* __restrict__ x,
                                               const float* __restrict__ y,
                                               unsigned short* __restrict__ ab2)
{
    const int bi = blockIdx.x;               // rb*10 + t
    const int rb = bi / NT, t = bi - rb * NT;
    for (int s = threadIdx.x; s < 512; s += 256) {
        const int kg = s >> 7, row = s & 127;
        const float* src = ((row < 64) ? x : y) + (size_t)(rb * 64 + (row & 63)) * D_;
        const int k0 = t * 32 + kg * 8;
        us8 hi, lo;
        #pragma unroll
        for (int j = 0; j < 8; ++j) {
            const int k = k0 + j;
            const float v = (k < D_) ? src[k] : 0.f;
            const unsigned short h = f2bf(v);
            hi[j] = h;
            lo[j] = f2bf(v - bf2f(h));
        }
        unsigned short* tb = ab2 + (size_t)bi * 8192;
        *(us8*)(tb + (size_t)s * 8)         = hi;
        *(us8*)(tb + (size_t)(512 + s) * 8) = lo;
    }
}

// ---------------------------------------------------------------------------
// prep: W1 -> split bf16 B-tiles. tile(e,t) = [2][4 kg][112 p][8 k]
// p >= 100 and k >= 300 zero-padded.
// ---------------------------------------------------------------------------
__global__ __launch_bounds__(256) void prep_w1(const float* __restrict__ w1,
                                               unsigned short* __restrict__ w1b2)
{
    const int bi = blockIdx.x;               // e*10 + t
    const int e = bi / NT, t = bi - e * NT;
    for (int s = threadIdx.x; s < 448; s += 256) {
        const int kg = s / 112, p = s - kg * 112;
        const int k0 = t * 32 + kg * 8;
        us8 hi, lo;
        #pragma unroll
        for (int j = 0; j < 8; ++j) {
            const int k = k0 + j;
            const float v = (p < P_ && k < D_) ? w1[((size_t)e * D_ + k) * P_ + p] : 0.f;
            const unsigned short h = f2bf(v);
            hi[j] = h;
            lo[j] = f2bf(v - bf2f(h));
        }
        unsigned short* tb = w1b2 + (size_t)bi * 7168;
        *(us8*)(tb + (size_t)s * 8)         = hi;
        *(us8*)(tb + (size_t)(448 + s) * 8) = lo;
    }
}

// ---------------------------------------------------------------------------
// gating softmax (fp32, proven in R1)
// ---------------------------------------------------------------------------
__global__ __launch_bounds__(128) void gate_kernel(
    const float* __restrict__ x, const float* __restrict__ y,
    const float* __restrict__ wall, float* __restrict__ wgate)
{
    __shared__ float s[D_];
    __shared__ float zv[128];
    __shared__ float red[128];
    const int b = blockIdx.x;
    const int tid = threadIdx.x;

    for (int d = tid; d < D_; d += 128)
        s[d] = x[(size_t)b * D_ + d] + y[(size_t)b * D_ + d];
    __syncthreads();

    float acc = 0.f;
    if (tid < E_)
        for (int d = 0; d < D_; ++d) acc += s[d] * wall[(size_t)d * E_ + tid];
    zv[tid] = (tid < E_) ? acc : -INFINITY;
    red[tid] = zv[tid];
    __syncthreads();
    for (int st = 64; st > 0; st >>= 1) {
        if (tid < st) red[tid] = fmaxf(red[tid], red[tid + st]);
        __syncthreads();
    }
    const float m = red[0];
    __syncthreads();
    const float ev = (tid < E_) ? expf(zv[tid] - m) : 0.f;
    red[tid] = ev;
    __syncthreads();
    for (int st = 64; st > 0; st >>= 1) {
        if (tid < st) red[tid] += red[tid + st];
        __syncthreads();
    }
    if (tid < E_) wgate[(size_t)b * E_ + tid] = ev / red[0];
}

// ---------------------------------------------------------------------------
// main fused kernel: grid (128, 100), 256 threads (4 waves).
// Phase A: split-bf16 MFMA projection: xp = xh*wh + xl*wh + xh*wl (fp32-grade)
// Phase B: cos + feat assembly (fp16 feat in LDS, fp32 math)
// Phase C: fp32 MLP 202->20->1, atomic add into out
// ---------------------------------------------------------------------------
__global__ __launch_bounds__(256) void moe_mfma_kernel(
    const float* __restrict__ tag,
    const unsigned short* __restrict__ ab2,
    const unsigned short* __restrict__ w1b2,
    const float* __restrict__ b1,
    const float* __restrict__ wh,
    const float* __restrict__ hb,
    const float* __restrict__ wo,
    const float* __restrict__ ob,
    const float* __restrict__ wgate,
    float* __restrict__ out)
{
    __shared__ __align__(16) unsigned short A_lds[2][8192];   // 2 x 16 KB (hi|lo)
    __shared__ __align__(16) unsigned short Bw_lds[2][7168];  // 2 x 14 KB (hi|lo)
    __shared__ __align__(16) _Float16 featl[64][212];         // fp16, stride 212
    __shared__ __align__(16) float swh[20][212];              // wh[e] transposed

    const int tid  = threadIdx.x;
    const int lane = tid & 63, w = tid >> 6;
    const int rb = blockIdx.x, e = blockIdx.y;
    const int b0 = rb * 64;
    const int li = lane & 15, kgq = lane >> 4;

    // zero feat pads [202..211]
    for (int k = tid; k < 640; k += 256) featl[k / 10][202 + k % 10] = (_Float16)0.f;

    // stage wh[e] transposed -> swh[h][f] (L2-hot; hides under phase A)
    for (int k = tid; k < 20 * 212; k += 256) {
        const int h = k / 212, f = k - h * 212;
        swh[h][f] = (f < F_) ? wh[((size_t)e * F_ + f) * H_ + h] : 0.f;
    }

    f32x4 accx[7], accy[7];
    #pragma unroll
    for (int ni = 0; ni < 7; ++ni) {
        accx[ni] = (f32x4){0.f, 0.f, 0.f, 0.f};
        accy[ni] = (f32x4){0.f, 0.f, 0.f, 0.f};
    }

    // per-lane ds_read bases (ushort units) within the hi block
    const int a_base = (kgq * 128 + w * 16 + li) * 8;
    const int b_base = (kgq * 112 + li) * 8;

    auto stage = [&](int tt, int bb) {
        const unsigned short* abase = ab2 + (size_t)(rb * NT + tt) * 8192 + lane * 8;
        const unsigned short* bbase = w1b2 + (size_t)(e * NT + tt) * 7168 + lane * 8;
        #pragma unroll
        for (int k = 0; k < 8; ++k) {
            const int i = w + 4 * k;           // wave-uniform, 0..31
            if (i < 16)      GLOAD16(abase + i * 512, &A_lds[bb][i * 512]);
            else if (i < 30) GLOAD16(bbase + (i - 16) * 512, &Bw_lds[bb][(i - 16) * 512]);
        }
    };

    // -------- phase A --------
    stage(0, 0);
    __syncthreads();                            // drains vmcnt -> buf0 ready
    for (int t = 0; t < NT; ++t) {
        const int bb = t & 1;
        if (t < NT - 1) stage(t + 1, bb ^ 1);   // issue next tile first
        const bf16x8 axh = *(const bf16x8*)(&A_lds[bb][a_base]);
        const bf16x8 axl = *(const bf16x8*)(&A_lds[bb][a_base + 4096]);
        const bf16x8 ayh = *(const bf16x8*)(&A_lds[bb][a_base + 512]);        // y rows
        const bf16x8 ayl = *(const bf16x8*)(&A_lds[bb][a_base + 512 + 4096]);
        #pragma unroll
        for (int ni = 0; ni < 7; ++ni) {
            const bf16x8 bh = *(const bf16x8*)(&Bw_lds[bb][b_base + ni * 128]);
            const bf16x8 bl = *(const bf16x8*)(&Bw_lds[bb][b_base + ni * 128 + 3584]);
            accx[ni] = __builtin_amdgcn_mfma_f32_16x16x32_bf16(axh, bh, accx[ni], 0, 0, 0);
            accx[ni] = __builtin_amdgcn_mfma_f32_16x16x32_bf16(axl, bh, accx[ni], 0, 0, 0);
            accx[ni] = __builtin_amdgcn_mfma_f32_16x16x32_bf16(axh, bl, accx[ni], 0, 0, 0);
            accy[ni] = __builtin_amdgcn_mfma_f32_16x16x32_bf16(ayh, bh, accy[ni], 0, 0, 0);
            accy[ni] = __builtin_amdgcn_mfma_f32_16x16x32_bf16(ayl, bh, accy[ni], 0, 0, 0);
            accy[ni] = __builtin_amdgcn_mfma_f32_16x16x32_bf16(ayh, bl, accy[ni], 0, 0, 0);
        }
        __syncthreads();                        // all waves done with bb; next tile landed
    }

    // -------- phase B: bias, feat, cos --------
    float pxx[4] = {0, 0, 0, 0}, pyy[4] = {0, 0, 0, 0}, pxy[4] = {0, 0, 0, 0};
    #pragma unroll
    for (int ni = 0; ni < 7; ++ni) {
        const int c = ni * 16 + li;
        if (c < P_) {
            const float bp = b1[(size_t)e * P_ + c];
            #pragma unroll
            for (int j = 0; j < 4; ++j) {
                const float xv = accx[ni][j] + bp;
                const float yv = accy[ni][j] + bp;
                const int r = w * 16 + kgq * 4 + j;   // C-frag row (m89 layout)
                featl[r][1 + c]   = (_Float16)(xv + yv);
                featl[r][101 + c] = (_Float16)fabsf(xv - yv);
                pxx[j] += xv * xv; pyy[j] += yv * yv; pxy[j] += xv * yv;
            }
        }
    }
    #pragma unroll
    for (int j = 0; j < 4; ++j) {
        #pragma unroll
        for (int m = 1; m < 16; m <<= 1) {
            pxx[j] += __shfl_xor(pxx[j], m);
            pyy[j] += __shfl_xor(pyy[j], m);
            pxy[j] += __shfl_xor(pxy[j], m);
        }
    }
    if (li == 0) {
        #pragma unroll
        for (int j = 0; j < 4; ++j) {
            const int r = w * 16 + kgq * 4 + j;
            const float nx = fmaxf(sqrtf(pxx[j]), 1e-8f);
            const float ny = fmaxf(sqrtf(pyy[j]), 1e-8f);
            featl[r][0]   = (_Float16)(pxy[j] / (nx * ny));
            featl[r][201] = (_Float16)tag[b0 + r];
        }
    }
    __syncthreads();

    // -------- phase C: hidden (202->20) + out (20->1) --------
    const int r  = tid >> 2;     // 0..63
    const int hq = tid & 3;
    float a[5];
    #pragma unroll
    for (int i = 0; i < 5; ++i) a[i] = hb[(size_t)e * H_ + hq + 4 * i];

    for (int f0 = 0; f0 < 212; f0 += 4) {
        const f16x4 fv = *(const f16x4*)(&featl[r][f0]);   // 4 f16, 8B aligned
        const float f0v = (float)fv[0];
        const float f1v = (float)fv[1];
        const float f2v = (float)fv[2];
        const float f3v = (float)fv[3];
        #pragma unroll
        for (int i = 0; i < 5; ++i) {
            const f32x4 wv = *(const f32x4*)(&swh[hq + 4 * i][f0]);
            a[i] += f0v * wv[0] + f1v * wv[1] + f2v * wv[2] + f3v * wv[3];
        }
    }
    float dsum = 0.f;
    #pragma unroll
    for (int i = 0; i < 5; ++i)
        dsum += fmaxf(a[i], 0.f) * wo[(size_t)e * H_ + hq + 4 * i];
    dsum += __shfl_xor(dsum, 1);
    dsum += __shfl_xor(dsum, 2);
    if (hq == 0) {
        const int b = b0 + r;
        atomicAdd(&out[b], wgate[(size_t)b * E_ + e] * (dsum + ob[e]));
    }
}

// ---------------------------------------------------------------------------
extern "C" void kernel_launch(void* const* d_in, const int* in_sizes, int n_in,
                              void* d_out, int out_size, void* d_ws, size_t ws_size,
                              hipStream_t stream)
{
    const float* x    = (const float*)d_in[0];
    const float* y    = (const float*)d_in[1];
    const float* tag  = (const float*)d_in[2];
    const float* w1   = (const float*)d_in[3];
    const float* b1   = (const float*)d_in[4];
    const float* wh   = (const float*)d_in[5];
    const float* hb   = (const float*)d_in[6];
    const float* wo   = (const float*)d_in[7];
    const float* ob   = (const float*)d_in[8];
    const float* wall = (const float*)d_in[9];

    float* out = (float*)d_out;
    char* ws = (char*)d_ws;
    float*          wgate = (float*)(ws + WG_OFF);
    unsigned short* ab2   = (unsigned short*)(ws + AB_OFF);
    unsigned short* w1b2  = (unsigned short*)(ws + W1_OFF);

    hipMemsetAsync(out, 0, (size_t)B_ * sizeof(float), stream);

    prep_xy<<<dim3(128 * NT), dim3(256), 0, stream>>>(x, y, ab2);
    prep_w1<<<dim3(E_ * NT), dim3(256), 0, stream>>>(w1, w1b2);
    gate_kernel<<<dim3(B_), dim3(128), 0, stream>>>(x, y, wall, wgate);
    moe_mfma_kernel<<<dim3(B_ / 64, E_), dim3(256), 0, stream>>>(
        tag, ab2, w1b2, b1, wh, hb, wo, ob, wgate, out);
}

// Round 6
// 674.852 us; speedup vs baseline: 6.5256x; 1.6860x over previous
//
#include <hip/hip_runtime.h>
#include <math.h>

#define B_ 8192
#define E_ 100
#define D_ 300
#define P_ 100
#define H_ 20
#define F_ 202   // 2P+2
#define NT 10    // K steps of 32 (300 padded to 320)

typedef __attribute__((ext_vector_type(8))) short bf16x8;
typedef __attribute__((ext_vector_type(4))) _Float16 f16x4;
typedef __attribute__((ext_vector_type(4))) float f32x4;
typedef __attribute__((ext_vector_type(8))) unsigned short us8;

// ---- workspace layout (bytes) ----
// A tiles: [128 rb][10 t][2 part(hi|lo)][4 kg][128 row][8 k] bf16 = 16 KB/tile
// B tiles: [100 e][10 t][2 part(hi|lo)][4 kg][112 p][8 k] bf16  = 14 KB/tile
#define WG_OFF 0                         // wgate [B][E] f32        (3,276,800)
#define AB_OFF 3276800                   // 128*10*8192 halves      (20,971,520)
#define W1_OFF (AB_OFF + 20971520)       // 100*10*7168 halves      (14,336,000)
#define PD_OFF (W1_OFF + 14336000)       // pd [E][B] f32           (3,276,800)
#define WS_NEEDED (PD_OFF + 3276800)     // 41,861,120 B

__device__ __forceinline__ unsigned short f2bf(float f) {
    unsigned int u = __float_as_uint(f);
    u = (u + 0x7FFF + ((u >> 16) & 1)) >> 16;   // RNE
    return (unsigned short)u;
}
__device__ __forceinline__ float bf2f(unsigned short h) {
    return __uint_as_float(((unsigned int)h) << 16);
}

#define GLOAD16(g, l) \
    __builtin_amdgcn_global_load_lds((const __attribute__((address_space(1))) unsigned int*)(g), \
                                     (__attribute__((address_space(3))) unsigned int*)(l), 16, 0, 0)

// ---------------------------------------------------------------------------
// prep: x,y -> split bf16 A-tiles. tile(rb,t) = [2][4 kg][128 row][8 k]
// rows 0..63 = x rows, 64..127 = y rows. k >= 300 zero-padded.  (proven R4)
// ---------------------------------------------------------------------------
__global__ __launch_bounds__(256) void prep_xy(const float* __restrict__ x,
                                               const float* __restrict__ y,
                                               unsigned short* __restrict__ ab2)
{
    const int bi = blockIdx.x;               // rb*10 + t
    const int rb = bi / NT, t = bi - rb * NT;
    for (int s = threadIdx.x; s < 512; s += 256) {
        const int kg = s >> 7, row = s & 127;
        const float* src = ((row < 64) ? x : y) + (size_t)(rb * 64 + (row & 63)) * D_;
        const int k0 = t * 32 + kg * 8;
        us8 hi, lo;
        #pragma unroll
        for (int j = 0; j < 8; ++j) {
            const int k = k0 + j;
            const float v = (k < D_) ? src[k] : 0.f;
            const unsigned short h = f2bf(v);
            hi[j] = h;
            lo[j] = f2bf(v - bf2f(h));
        }
        unsigned short* tb = ab2 + (size_t)bi * 8192;
        *(us8*)(tb + (size_t)s * 8)         = hi;
        *(us8*)(tb + (size_t)(512 + s) * 8) = lo;
    }
}

// ---------------------------------------------------------------------------
// prep: W1 -> split bf16 B-tiles. tile(e,t) = [2][4 kg][112 p][8 k]  (proven R4)
// ---------------------------------------------------------------------------
__global__ __launch_bounds__(256) void prep_w1(const float* __restrict__ w1,
                                               unsigned short* __restrict__ w1b2)
{
    const int bi = blockIdx.x;               // e*10 + t
    const int e = bi / NT, t = bi - e * NT;
    for (int s = threadIdx.x; s < 448; s += 256) {
        const int kg = s / 112, p = s - kg * 112;
        const int k0 = t * 32 + kg * 8;
        us8 hi, lo;
        #pragma unroll
        for (int j = 0; j < 8; ++j) {
            const int k = k0 + j;
            const float v = (p < P_ && k < D_) ? w1[((size_t)e * D_ + k) * P_ + p] : 0.f;
            const unsigned short h = f2bf(v);
            hi[j] = h;
            lo[j] = f2bf(v - bf2f(h));
        }
        unsigned short* tb = w1b2 + (size_t)bi * 7168;
        *(us8*)(tb + (size_t)s * 8)         = hi;
        *(us8*)(tb + (size_t)(448 + s) * 8) = lo;
    }
}

// ---------------------------------------------------------------------------
// gating softmax (fp32, proven)
// ---------------------------------------------------------------------------
__global__ __launch_bounds__(128) void gate_kernel(
    const float* __restrict__ x, const float* __restrict__ y,
    const float* __restrict__ wall, float* __restrict__ wgate)
{
    __shared__ float s[D_];
    __shared__ float zv[128];
    __shared__ float red[128];
    const int b = blockIdx.x;
    const int tid = threadIdx.x;

    for (int d = tid; d < D_; d += 128)
        s[d] = x[(size_t)b * D_ + d] + y[(size_t)b * D_ + d];
    __syncthreads();

    float acc = 0.f;
    if (tid < E_)
        for (int d = 0; d < D_; ++d) acc += s[d] * wall[(size_t)d * E_ + tid];
    zv[tid] = (tid < E_) ? acc : -INFINITY;
    red[tid] = zv[tid];
    __syncthreads();
    for (int st = 64; st > 0; st >>= 1) {
        if (tid < st) red[tid] = fmaxf(red[tid], red[tid + st]);
        __syncthreads();
    }
    const float m = red[0];
    __syncthreads();
    const float ev = (tid < E_) ? expf(zv[tid] - m) : 0.f;
    red[tid] = ev;
    __syncthreads();
    for (int st = 64; st > 0; st >>= 1) {
        if (tid < st) red[tid] += red[tid + st];
        __syncthreads();
    }
    if (tid < E_) wgate[(size_t)b * E_ + tid] = ev / red[0];
}

// ---------------------------------------------------------------------------
// main fused kernel: grid (128, 100), 256 threads (4 waves).
// R4 numerics, single-buffered staging, separate (non-aliased) featl/swh.
// LDS total 74,816 B -> 2 blocks/CU (8 waves/CU).
// USE_PD=1: deterministic pd[e][b] output; else R4's atomicAdd path.
// ---------------------------------------------------------------------------
template<bool USE_PD>
__global__ __launch_bounds__(256) void moe_mfma_kernel(
    const float* __restrict__ tag,
    const unsigned short* __restrict__ ab2,
    const unsigned short* __restrict__ w1b2,
    const float* __restrict__ b1,
    const float* __restrict__ wh,
    const float* __restrict__ hb,
    const float* __restrict__ wo,
    const float* __restrict__ ob,
    const float* __restrict__ wgate,
    float* __restrict__ pd,
    float* __restrict__ out)
{
    __shared__ __align__(16) unsigned short A_lds[8192];    // 16 KB (hi|lo)
    __shared__ __align__(16) unsigned short Bw_lds[7168];   // 14 KB (hi|lo)
    __shared__ __align__(16) _Float16 featl[64][212];       // 27,136 B
    __shared__ __align__(16) float swh[20][212];            // 16,960 B

    const int tid  = threadIdx.x;
    const int lane = tid & 63, w = tid >> 6;
    const int rb = blockIdx.x, e = blockIdx.y;
    const int b0 = rb * 64;
    const int li = lane & 15, kgq = lane >> 4;

    // zero feat pads [202..211]
    for (int k = tid; k < 640; k += 256) featl[k / 10][202 + k % 10] = (_Float16)0.f;

    // stage wh[e] transposed -> swh[h][f] (L2-hot; hides under phase A)
    for (int k = tid; k < 20 * 212; k += 256) {
        const int h = k / 212, f = k - h * 212;
        swh[h][f] = (f < F_) ? wh[((size_t)e * F_ + f) * H_ + h] : 0.f;
    }

    f32x4 accx[7], accy[7];
    #pragma unroll
    for (int ni = 0; ni < 7; ++ni) {
        accx[ni] = (f32x4){0.f, 0.f, 0.f, 0.f};
        accy[ni] = (f32x4){0.f, 0.f, 0.f, 0.f};
    }

    // per-lane ds_read bases (ushort units) within the hi block
    const int a_base = (kgq * 128 + w * 16 + li) * 8;
    const int b_base = (kgq * 112 + li) * 8;

    auto stage = [&](int tt) {
        const unsigned short* abase = ab2 + (size_t)(rb * NT + tt) * 8192 + lane * 8;
        const unsigned short* bbase = w1b2 + (size_t)(e * NT + tt) * 7168 + lane * 8;
        #pragma unroll
        for (int k = 0; k < 8; ++k) {
            const int i = w + 4 * k;           // wave-uniform, 0..31
            if (i < 16)      GLOAD16(abase + i * 512, &A_lds[i * 512]);
            else if (i < 30) GLOAD16(bbase + (i - 16) * 512, &Bw_lds[(i - 16) * 512]);
        }
    };

    // -------- phase A: split-bf16 MFMA projection (single-buffered) --------
    for (int t = 0; t < NT; ++t) {
        stage(t);
        __syncthreads();                        // vmcnt drain -> buffer ready
        const bf16x8 axh = *(const bf16x8*)(&A_lds[a_base]);
        const bf16x8 axl = *(const bf16x8*)(&A_lds[a_base + 4096]);
        const bf16x8 ayh = *(const bf16x8*)(&A_lds[a_base + 512]);        // y rows
        const bf16x8 ayl = *(const bf16x8*)(&A_lds[a_base + 512 + 4096]);
        #pragma unroll
        for (int ni = 0; ni < 7; ++ni) {
            const bf16x8 bh = *(const bf16x8*)(&Bw_lds[b_base + ni * 128]);
            const bf16x8 bl = *(const bf16x8*)(&Bw_lds[b_base + ni * 128 + 3584]);
            accx[ni] = __builtin_amdgcn_mfma_f32_16x16x32_bf16(axh, bh, accx[ni], 0, 0, 0);
            accx[ni] = __builtin_amdgcn_mfma_f32_16x16x32_bf16(axl, bh, accx[ni], 0, 0, 0);
            accx[ni] = __builtin_amdgcn_mfma_f32_16x16x32_bf16(axh, bl, accx[ni], 0, 0, 0);
            accy[ni] = __builtin_amdgcn_mfma_f32_16x16x32_bf16(ayh, bh, accy[ni], 0, 0, 0);
            accy[ni] = __builtin_amdgcn_mfma_f32_16x16x32_bf16(ayl, bh, accy[ni], 0, 0, 0);
            accy[ni] = __builtin_amdgcn_mfma_f32_16x16x32_bf16(ayh, bl, accy[ni], 0, 0, 0);
        }
        __syncthreads();                        // all waves done reading before overwrite
    }

    // -------- phase B: bias, feat, cos --------
    float pxx[4] = {0, 0, 0, 0}, pyy[4] = {0, 0, 0, 0}, pxy[4] = {0, 0, 0, 0};
    #pragma unroll
    for (int ni = 0; ni < 7; ++ni) {
        const int c = ni * 16 + li;
        if (c < P_) {
            const float bp = b1[(size_t)e * P_ + c];
            #pragma unroll
            for (int j = 0; j < 4; ++j) {
                const float xv = accx[ni][j] + bp;
                const float yv = accy[ni][j] + bp;
                const int r = w * 16 + kgq * 4 + j;   // C-frag row (m89 layout)
                featl[r][1 + c]   = (_Float16)(xv + yv);
                featl[r][101 + c] = (_Float16)fabsf(xv - yv);
                pxx[j] += xv * xv; pyy[j] += yv * yv; pxy[j] += xv * yv;
            }
        }
    }
    #pragma unroll
    for (int j = 0; j < 4; ++j) {
        #pragma unroll
        for (int m = 1; m < 16; m <<= 1) {
            pxx[j] += __shfl_xor(pxx[j], m);
            pyy[j] += __shfl_xor(pyy[j], m);
            pxy[j] += __shfl_xor(pxy[j], m);
        }
    }
    if (li == 0) {
        #pragma unroll
        for (int j = 0; j < 4; ++j) {
            const int r = w * 16 + kgq * 4 + j;
            const float nx = fmaxf(sqrtf(pxx[j]), 1e-8f);
            const float ny = fmaxf(sqrtf(pyy[j]), 1e-8f);
            featl[r][0]   = (_Float16)(pxy[j] / (nx * ny));
            featl[r][201] = (_Float16)tag[b0 + r];
        }
    }
    __syncthreads();

    // -------- phase C: hidden (202->20) + out (20->1) --------
    const int r  = tid >> 2;     // 0..63
    const int hq = tid & 3;
    float a[5];
    #pragma unroll
    for (int i = 0; i < 5; ++i) a[i] = hb[(size_t)e * H_ + hq + 4 * i];

    for (int f0 = 0; f0 < 212; f0 += 4) {
        const f16x4 fv = *(const f16x4*)(&featl[r][f0]);   // 4 f16, 8B aligned
        const float f0v = (float)fv[0];
        const float f1v = (float)fv[1];
        const float f2v = (float)fv[2];
        const float f3v = (float)fv[3];
        #pragma unroll
        for (int i = 0; i < 5; ++i) {
            const f32x4 wv = *(const f32x4*)(&swh[hq + 4 * i][f0]);
            a[i] += f0v * wv[0] + f1v * wv[1] + f2v * wv[2] + f3v * wv[3];
        }
    }
    float dsum = 0.f;
    #pragma unroll
    for (int i = 0; i < 5; ++i)
        dsum += fmaxf(a[i], 0.f) * wo[(size_t)e * H_ + hq + 4 * i];
    dsum += __shfl_xor(dsum, 1);
    dsum += __shfl_xor(dsum, 2);
    if (hq == 0) {
        const int b = b0 + r;
        const float v = wgate[(size_t)b * E_ + e] * (dsum + ob[e]);
        if (USE_PD) pd[(size_t)e * B_ + b] = v;
        else        atomicAdd(&out[b], v);
    }
}

// ---------------------------------------------------------------------------
// deterministic reduction over experts (fixed e-ascending order)
// ---------------------------------------------------------------------------
__global__ __launch_bounds__(256) void reduce_kernel(const float* __restrict__ pd,
                                                     float* __restrict__ out)
{
    const int b = blockIdx.x * 256 + threadIdx.x;
    float s = 0.f;
    for (int e = 0; e < E_; ++e) s += pd[(size_t)e * B_ + b];
    out[b] = s;
}

// ---------------------------------------------------------------------------
extern "C" void kernel_launch(void* const* d_in, const int* in_sizes, int n_in,
                              void* d_out, int out_size, void* d_ws, size_t ws_size,
                              hipStream_t stream)
{
    const float* x    = (const float*)d_in[0];
    const float* y    = (const float*)d_in[1];
    const float* tag  = (const float*)d_in[2];
    const float* w1   = (const float*)d_in[3];
    const float* b1   = (const float*)d_in[4];
    const float* wh   = (const float*)d_in[5];
    const float* hb   = (const float*)d_in[6];
    const float* wo   = (const float*)d_in[7];
    const float* ob   = (const float*)d_in[8];
    const float* wall = (const float*)d_in[9];

    float* out = (float*)d_out;
    char* ws = (char*)d_ws;
    float*          wgate = (float*)(ws + WG_OFF);
    unsigned short* ab2   = (unsigned short*)(ws + AB_OFF);
    unsigned short* w1b2  = (unsigned short*)(ws + W1_OFF);
    float*          pd    = (float*)(ws + PD_OFF);

    const bool use_pd = (ws_size >= (size_t)WS_NEEDED);

    prep_xy<<<dim3(128 * NT), dim3(256), 0, stream>>>(x, y, ab2);
    prep_w1<<<dim3(E_ * NT), dim3(256), 0, stream>>>(w1, w1b2);
    gate_kernel<<<dim3(B_), dim3(128), 0, stream>>>(x, y, wall, wgate);

    if (use_pd) {
        moe_mfma_kernel<true><<<dim3(B_ / 64, E_), dim3(256), 0, stream>>>(
            tag, ab2, w1b2, b1, wh, hb, wo, ob, wgate, pd, out);
        reduce_kernel<<<dim3(B_ / 256), dim3(256), 0, stream>>>(pd, out);
    } else {
        hipMemsetAsync(out, 0, (size_t)B_ * sizeof(float), stream);
        moe_mfma_kernel<false><<<dim3(B_ / 64, E_), dim3(256), 0, stream>>>(
            tag, ab2, w1b2, b1, wh, hb, wo, ob, wgate, pd, out);
    }
}

// Round 7
// 573.792 us; speedup vs baseline: 7.6749x; 1.1761x over previous
//
#include <hip/hip_runtime.h>
#include <math.h>

#define B_ 8192
#define E_ 100
#define D_ 300
#define P_ 100
#define H_ 20
#define F_ 202   // 2P+2
#define NT 10    // K steps of 32 (300 padded to 320)

typedef __attribute__((ext_vector_type(8))) short bf16x8;
typedef __attribute__((ext_vector_type(8))) _Float16 f16x8;
typedef __attribute__((ext_vector_type(4))) float f32x4;
typedef __attribute__((ext_vector_type(8))) unsigned short us8;

// ---- workspace layout (bytes) ----
#define WG_OFF 0                         // wgate [B][E] f32        (3,276,800)
#define AB_OFF 3276800                   // 128*10*8192 halves      (20,971,520)
#define W1_OFF (AB_OFF + 20971520)       // 100*10*7168 halves      (14,336,000)
#define PD_OFF (W1_OFF + 14336000)       // pd [E][B] f32           (3,276,800)
#define WS_NEEDED (PD_OFF + 3276800)     // 41,861,120 B

__device__ __forceinline__ unsigned short f2bf(float f) {
    unsigned int u = __float_as_uint(f);
    u = (u + 0x7FFF + ((u >> 16) & 1)) >> 16;   // RNE
    return (unsigned short)u;
}
__device__ __forceinline__ float bf2f(unsigned short h) {
    return __uint_as_float(((unsigned int)h) << 16);
}

#define GLOAD16(g, l) \
    __builtin_amdgcn_global_load_lds((const __attribute__((address_space(1))) unsigned int*)(g), \
                                     (__attribute__((address_space(3))) unsigned int*)(l), 16, 0, 0)

// ---------------------------------------------------------------------------
// prep: x,y -> split bf16 A-tiles. tile(rb,t) = [2][4 kg][128 row][8 k] (proven)
// ---------------------------------------------------------------------------
__global__ __launch_bounds__(256) void prep_xy(const float* __restrict__ x,
                                               const float* __restrict__ y,
                                               unsigned short* __restrict__ ab2)
{
    const int bi = blockIdx.x;               // rb*10 + t
    const int rb = bi / NT, t = bi - rb * NT;
    for (int s = threadIdx.x; s < 512; s += 256) {
        const int kg = s >> 7, row = s & 127;
        const float* src = ((row < 64) ? x : y) + (size_t)(rb * 64 + (row & 63)) * D_;
        const int k0 = t * 32 + kg * 8;
        us8 hi, lo;
        #pragma unroll
        for (int j = 0; j < 8; ++j) {
            const int k = k0 + j;
            const float v = (k < D_) ? src[k] : 0.f;
            const unsigned short h = f2bf(v);
            hi[j] = h;
            lo[j] = f2bf(v - bf2f(h));
        }
        unsigned short* tb = ab2 + (size_t)bi * 8192;
        *(us8*)(tb + (size_t)s * 8)         = hi;
        *(us8*)(tb + (size_t)(512 + s) * 8) = lo;
    }
}

// ---------------------------------------------------------------------------
// prep: W1 -> split bf16 B-tiles. tile(e,t) = [2][4 kg][112 p][8 k] (proven)
// ---------------------------------------------------------------------------
__global__ __launch_bounds__(256) void prep_w1(const float* __restrict__ w1,
                                               unsigned short* __restrict__ w1b2)
{
    const int bi = blockIdx.x;               // e*10 + t
    const int e = bi / NT, t = bi - e * NT;
    for (int s = threadIdx.x; s < 448; s += 256) {
        const int kg = s / 112, p = s - kg * 112;
        const int k0 = t * 32 + kg * 8;
        us8 hi, lo;
        #pragma unroll
        for (int j = 0; j < 8; ++j) {
            const int k = k0 + j;
            const float v = (p < P_ && k < D_) ? w1[((size_t)e * D_ + k) * P_ + p] : 0.f;
            const unsigned short h = f2bf(v);
            hi[j] = h;
            lo[j] = f2bf(v - bf2f(h));
        }
        unsigned short* tb = w1b2 + (size_t)bi * 7168;
        *(us8*)(tb + (size_t)s * 8)         = hi;
        *(us8*)(tb + (size_t)(448 + s) * 8) = lo;
    }
}

// ---------------------------------------------------------------------------
// gating softmax (fp32, proven)
// ---------------------------------------------------------------------------
__global__ __launch_bounds__(128) void gate_kernel(
    const float* __restrict__ x, const float* __restrict__ y,
    const float* __restrict__ wall, float* __restrict__ wgate)
{
    __shared__ float s[D_];
    __shared__ float zv[128];
    __shared__ float red[128];
    const int b = blockIdx.x;
    const int tid = threadIdx.x;

    for (int d = tid; d < D_; d += 128)
        s[d] = x[(size_t)b * D_ + d] + y[(size_t)b * D_ + d];
    __syncthreads();

    float acc = 0.f;
    if (tid < E_)
        for (int d = 0; d < D_; ++d) acc += s[d] * wall[(size_t)d * E_ + tid];
    zv[tid] = (tid < E_) ? acc : -INFINITY;
    red[tid] = zv[tid];
    __syncthreads();
    for (int st = 64; st > 0; st >>= 1) {
        if (tid < st) red[tid] = fmaxf(red[tid], red[tid + st]);
        __syncthreads();
    }
    const float m = red[0];
    __syncthreads();
    const float ev = (tid < E_) ? expf(zv[tid] - m) : 0.f;
    red[tid] = ev;
    __syncthreads();
    for (int st = 64; st > 0; st >>= 1) {
        if (tid < st) red[tid] += red[tid + st];
        __syncthreads();
    }
    if (tid < E_) wgate[(size_t)b * E_ + tid] = ev / red[0];
}

// ---------------------------------------------------------------------------
// main fused kernel: grid (128, 100), 256 threads (4 waves).
// Phase A: split-bf16 MFMA projection (frozen from R6)
// Phase B: cos + feat assembly, fp16 feat in LDS (frozen from R6)
// Phase C: fp16 MFMA hidden layer (feat[64x202] x wh[202x20], wh split hi/lo)
//          + relu + out-layer epilogue via 16-lane shfl reduce
// LDS: 16,384 + 14,336 + 29,696 + 18,560 = 78,976 B -> 2 blocks/CU.
// ---------------------------------------------------------------------------
template<bool USE_PD>
__global__ __launch_bounds__(256) void moe_mfma_kernel(
    const float* __restrict__ tag,
    const unsigned short* __restrict__ ab2,
    const unsigned short* __restrict__ w1b2,
    const float* __restrict__ b1,
    const float* __restrict__ wh,
    const float* __restrict__ hb,
    const float* __restrict__ wo,
    const float* __restrict__ ob,
    const float* __restrict__ wgate,
    float* __restrict__ pd,
    float* __restrict__ out)
{
    __shared__ __align__(16) unsigned short A_lds[8192];    // 16 KB (hi|lo)
    __shared__ __align__(16) unsigned short Bw_lds[7168];   // 14 KB (hi|lo)
    __shared__ __align__(16) _Float16 featl[64][232];       // 29,696 B (k-pad 232)
    __shared__ __align__(16) _Float16 swh2[2][20][232];     // 18,560 B (hi|lo wh^T)

    const int tid  = threadIdx.x;
    const int lane = tid & 63, w = tid >> 6;
    const int rb = blockIdx.x, e = blockIdx.y;
    const int b0 = rb * 64;
    const int li = lane & 15, kgq = lane >> 4;

    // zero feat k-pads [202..231]
    for (int k = tid; k < 64 * 30; k += 256) featl[k / 30][202 + k % 30] = (_Float16)0.f;

    // stage wh[e] as split fp16, transposed: swh2[part][h][f] (hides under phase A)
    for (int k = tid; k < 20 * 232; k += 256) {
        const int h = k / 232, f = k - h * 232;
        const float v = (f < F_) ? wh[((size_t)e * F_ + f) * H_ + h] : 0.f;
        const _Float16 vh = (_Float16)v;
        swh2[0][h][f] = vh;
        swh2[1][h][f] = (_Float16)(v - (float)vh);
    }

    f32x4 accx[7], accy[7];
    #pragma unroll
    for (int ni = 0; ni < 7; ++ni) {
        accx[ni] = (f32x4){0.f, 0.f, 0.f, 0.f};
        accy[ni] = (f32x4){0.f, 0.f, 0.f, 0.f};
    }

    // per-lane ds_read bases (ushort units) within the hi block
    const int a_base = (kgq * 128 + w * 16 + li) * 8;
    const int b_base = (kgq * 112 + li) * 8;

    auto stage = [&](int tt) {
        const unsigned short* abase = ab2 + (size_t)(rb * NT + tt) * 8192 + lane * 8;
        const unsigned short* bbase = w1b2 + (size_t)(e * NT + tt) * 7168 + lane * 8;
        #pragma unroll
        for (int k = 0; k < 8; ++k) {
            const int i = w + 4 * k;           // wave-uniform, 0..31
            if (i < 16)      GLOAD16(abase + i * 512, &A_lds[i * 512]);
            else if (i < 30) GLOAD16(bbase + (i - 16) * 512, &Bw_lds[(i - 16) * 512]);
        }
    };

    // -------- phase A: split-bf16 MFMA projection (single-buffered, frozen) ----
    for (int t = 0; t < NT; ++t) {
        stage(t);
        __syncthreads();                        // vmcnt drain -> buffer ready
        const bf16x8 axh = *(const bf16x8*)(&A_lds[a_base]);
        const bf16x8 axl = *(const bf16x8*)(&A_lds[a_base + 4096]);
        const bf16x8 ayh = *(const bf16x8*)(&A_lds[a_base + 512]);        // y rows
        const bf16x8 ayl = *(const bf16x8*)(&A_lds[a_base + 512 + 4096]);
        #pragma unroll
        for (int ni = 0; ni < 7; ++ni) {
            const bf16x8 bh = *(const bf16x8*)(&Bw_lds[b_base + ni * 128]);
            const bf16x8 bl = *(const bf16x8*)(&Bw_lds[b_base + ni * 128 + 3584]);
            accx[ni] = __builtin_amdgcn_mfma_f32_16x16x32_bf16(axh, bh, accx[ni], 0, 0, 0);
            accx[ni] = __builtin_amdgcn_mfma_f32_16x16x32_bf16(axl, bh, accx[ni], 0, 0, 0);
            accx[ni] = __builtin_amdgcn_mfma_f32_16x16x32_bf16(axh, bl, accx[ni], 0, 0, 0);
            accy[ni] = __builtin_amdgcn_mfma_f32_16x16x32_bf16(ayh, bh, accy[ni], 0, 0, 0);
            accy[ni] = __builtin_amdgcn_mfma_f32_16x16x32_bf16(ayl, bh, accy[ni], 0, 0, 0);
            accy[ni] = __builtin_amdgcn_mfma_f32_16x16x32_bf16(ayh, bl, accy[ni], 0, 0, 0);
        }
        __syncthreads();                        // all waves done reading before overwrite
    }

    // -------- phase B: bias, feat, cos (frozen) --------
    float pxx[4] = {0, 0, 0, 0}, pyy[4] = {0, 0, 0, 0}, pxy[4] = {0, 0, 0, 0};
    #pragma unroll
    for (int ni = 0; ni < 7; ++ni) {
        const int c = ni * 16 + li;
        if (c < P_) {
            const float bp = b1[(size_t)e * P_ + c];
            #pragma unroll
            for (int j = 0; j < 4; ++j) {
                const float xv = accx[ni][j] + bp;
                const float yv = accy[ni][j] + bp;
                const int r = w * 16 + kgq * 4 + j;   // C-frag row (m89 layout)
                featl[r][1 + c]   = (_Float16)(xv + yv);
                featl[r][101 + c] = (_Float16)fabsf(xv - yv);
                pxx[j] += xv * xv; pyy[j] += yv * yv; pxy[j] += xv * yv;
            }
        }
    }
    #pragma unroll
    for (int j = 0; j < 4; ++j) {
        #pragma unroll
        for (int m = 1; m < 16; m <<= 1) {
            pxx[j] += __shfl_xor(pxx[j], m);
            pyy[j] += __shfl_xor(pyy[j], m);
            pxy[j] += __shfl_xor(pxy[j], m);
        }
    }
    if (li == 0) {
        #pragma unroll
        for (int j = 0; j < 4; ++j) {
            const int r = w * 16 + kgq * 4 + j;
            const float nx = fmaxf(sqrtf(pxx[j]), 1e-8f);
            const float ny = fmaxf(sqrtf(pyy[j]), 1e-8f);
            featl[r][0]   = (_Float16)(pxy[j] / (nx * ny));
            featl[r][201] = (_Float16)tag[b0 + r];
        }
    }
    __syncthreads();

    // -------- phase C: hidden (202->20) via fp16 MFMA + out (20->1) --------
    // A = feat (mtile = w: rows w*16..w*16+15), B = wh^T split (N=20 in 2 ntiles)
    const int h1 = 16 + li;
    const bool v1 = (h1 < H_);
    const int h1c = v1 ? h1 : (H_ - 1);     // clamped in-bounds row for invalid lanes

    f32x4 acc0 = (f32x4){0.f, 0.f, 0.f, 0.f};
    f32x4 acc1 = (f32x4){0.f, 0.f, 0.f, 0.f};
    #pragma unroll
    for (int kt = 0; kt < 7; ++kt) {
        const int ko = kt * 32 + kgq * 8;
        const f16x8 af  = *(const f16x8*)(&featl[w * 16 + li][ko]);
        const f16x8 b0h = *(const f16x8*)(&swh2[0][li][ko]);
        const f16x8 b0l = *(const f16x8*)(&swh2[1][li][ko]);
        acc0 = __builtin_amdgcn_mfma_f32_16x16x32_f16(af, b0h, acc0, 0, 0, 0);
        acc0 = __builtin_amdgcn_mfma_f32_16x16x32_f16(af, b0l, acc0, 0, 0, 0);
        f16x8 b1h = *(const f16x8*)(&swh2[0][h1c][ko]);
        f16x8 b1l = *(const f16x8*)(&swh2[1][h1c][ko]);
        if (!v1) {                              // zero pad-cols 20..31
            b1h = (f16x8)(_Float16)0.f;
            b1l = (f16x8)(_Float16)0.f;
        }
        acc1 = __builtin_amdgcn_mfma_f32_16x16x32_f16(af, b1h, acc1, 0, 0, 0);
        acc1 = __builtin_amdgcn_mfma_f32_16x16x32_f16(af, b1l, acc1, 0, 0, 0);
    }

    // epilogue: bias + relu + wo, reduce over h (16 lanes), write pd/out
    const float hb0 = hb[(size_t)e * H_ + li];
    const float wo0 = wo[(size_t)e * H_ + li];
    const float hb1 = v1 ? hb[(size_t)e * H_ + h1] : 0.f;
    const float wo1 = v1 ? wo[(size_t)e * H_ + h1] : 0.f;
    #pragma unroll
    for (int j = 0; j < 4; ++j) {
        float t = fmaxf(acc0[j] + hb0, 0.f) * wo0;
        if (v1) t += fmaxf(acc1[j] + hb1, 0.f) * wo1;
        t += __shfl_xor(t, 1);
        t += __shfl_xor(t, 2);
        t += __shfl_xor(t, 4);
        t += __shfl_xor(t, 8);
        if (li == 0) {
            const int r = w * 16 + kgq * 4 + j;   // C-frag row
            const int b = b0 + r;
            const float v = wgate[(size_t)b * E_ + e] * (t + ob[e]);
            if (USE_PD) pd[(size_t)e * B_ + b] = v;
            else        atomicAdd(&out[b], v);
        }
    }
}

// ---------------------------------------------------------------------------
// deterministic reduction over experts (fixed e-ascending order)
// ---------------------------------------------------------------------------
__global__ __launch_bounds__(256) void reduce_kernel(const float* __restrict__ pd,
                                                     float* __restrict__ out)
{
    const int b = blockIdx.x * 256 + threadIdx.x;
    float s = 0.f;
    for (int e = 0; e < E_; ++e) s += pd[(size_t)e * B_ + b];
    out[b] = s;
}

// ---------------------------------------------------------------------------
extern "C" void kernel_launch(void* const* d_in, const int* in_sizes, int n_in,
                              void* d_out, int out_size, void* d_ws, size_t ws_size,
                              hipStream_t stream)
{
    const float* x    = (const float*)d_in[0];
    const float* y    = (const float*)d_in[1];
    const float* tag  = (const float*)d_in[2];
    const float* w1   = (const float*)d_in[3];
    const float* b1   = (const float*)d_in[4];
    const float* wh   = (const float*)d_in[5];
    const float* hb   = (const float*)d_in[6];
    const float* wo   = (const float*)d_in[7];
    const float* ob   = (const float*)d_in[8];
    const float* wall = (const float*)d_in[9];

    float* out = (float*)d_out;
    char* ws = (char*)d_ws;
    float*          wgate = (float*)(ws + WG_OFF);
    unsigned short* ab2   = (unsigned short*)(ws + AB_OFF);
    unsigned short* w1b2  = (unsigned short*)(ws + W1_OFF);
    float*          pd    = (float*)(ws + PD_OFF);

    const bool use_pd = (ws_size >= (size_t)WS_NEEDED);

    prep_xy<<<dim3(128 * NT), dim3(256), 0, stream>>>(x, y, ab2);
    prep_w1<<<dim3(E_ * NT), dim3(256), 0, stream>>>(w1, w1b2);
    gate_kernel<<<dim3(B_), dim3(128), 0, stream>>>(x, y, wall, wgate);

    if (use_pd) {
        moe_mfma_kernel<true><<<dim3(B_ / 64, E_), dim3(256), 0, stream>>>(
            tag, ab2, w1b2, b1, wh, hb, wo, ob, wgate, pd, out);
        reduce_kernel<<<dim3(B_ / 256), dim3(256), 0, stream>>>(pd, out);
    } else {
        hipMemsetAsync(out, 0, (size_t)B_ * sizeof(float), stream);
        moe_mfma_kernel<false><<<dim3(B_ / 64, E_), dim3(256), 0, stream>>>(
            tag, ab2, w1b2, b1, wh, hb, wo, ob, wgate, pd, out);
    }
}

// Round 8
// 532.804 us; speedup vs baseline: 8.2654x; 1.0769x over previous
//
#include <hip/hip_runtime.h>
#include <math.h>

#define B_ 8192
#define E_ 100
#define D_ 300
#define P_ 100
#define H_ 20
#define F_ 202   // 2P+2
#define NT 10    // K steps of 32 (300 padded to 320)

typedef __attribute__((ext_vector_type(8))) short bf16x8;
typedef __attribute__((ext_vector_type(8))) _Float16 f16x8;
typedef __attribute__((ext_vector_type(4))) float f32x4;
typedef __attribute__((ext_vector_type(8))) unsigned short us8;

// ---- workspace layout (bytes) ----
#define WG_OFF 0                         // wgate [B][E] f32        (3,276,800)
#define AB_OFF 3276800                   // 128*10*8192 halves      (20,971,520)
#define W1_OFF (AB_OFF + 20971520)       // 100*10*7168 halves      (14,336,000)
#define PD_OFF (W1_OFF + 14336000)       // pd [E][B] f32           (3,276,800)
#define WS_NEEDED (PD_OFF + 3276800)     // 41,861,120 B

__device__ __forceinline__ unsigned short f2bf(float f) {
    unsigned int u = __float_as_uint(f);
    u = (u + 0x7FFF + ((u >> 16) & 1)) >> 16;   // RNE
    return (unsigned short)u;
}
__device__ __forceinline__ float bf2f(unsigned short h) {
    return __uint_as_float(((unsigned int)h) << 16);
}

#define GLOAD16(g, l) \
    __builtin_amdgcn_global_load_lds((const __attribute__((address_space(1))) unsigned int*)(g), \
                                     (__attribute__((address_space(3))) unsigned int*)(l), 16, 0, 0)

// ---------------------------------------------------------------------------
// prep: x,y -> split bf16 A-tiles. tile(rb,t) = [2][4 kg][128 row][8 k] (proven)
// ---------------------------------------------------------------------------
__global__ __launch_bounds__(256) void prep_xy(const float* __restrict__ x,
                                               const float* __restrict__ y,
                                               unsigned short* __restrict__ ab2)
{
    const int bi = blockIdx.x;               // rb*10 + t
    const int rb = bi / NT, t = bi - rb * NT;
    for (int s = threadIdx.x; s < 512; s += 256) {
        const int kg = s >> 7, row = s & 127;
        const float* src = ((row < 64) ? x : y) + (size_t)(rb * 64 + (row & 63)) * D_;
        const int k0 = t * 32 + kg * 8;
        us8 hi, lo;
        #pragma unroll
        for (int j = 0; j < 8; ++j) {
            const int k = k0 + j;
            const float v = (k < D_) ? src[k] : 0.f;
            const unsigned short h = f2bf(v);
            hi[j] = h;
            lo[j] = f2bf(v - bf2f(h));
        }
        unsigned short* tb = ab2 + (size_t)bi * 8192;
        *(us8*)(tb + (size_t)s * 8)         = hi;
        *(us8*)(tb + (size_t)(512 + s) * 8) = lo;
    }
}

// ---------------------------------------------------------------------------
// prep: W1 -> split bf16 B-tiles. tile(e,t) = [2][4 kg][112 p][8 k] (proven)
// ---------------------------------------------------------------------------
__global__ __launch_bounds__(256) void prep_w1(const float* __restrict__ w1,
                                               unsigned short* __restrict__ w1b2)
{
    const int bi = blockIdx.x;               // e*10 + t
    const int e = bi / NT, t = bi - e * NT;
    for (int s = threadIdx.x; s < 448; s += 256) {
        const int kg = s / 112, p = s - kg * 112;
        const int k0 = t * 32 + kg * 8;
        us8 hi, lo;
        #pragma unroll
        for (int j = 0; j < 8; ++j) {
            const int k = k0 + j;
            const float v = (p < P_ && k < D_) ? w1[((size_t)e * D_ + k) * P_ + p] : 0.f;
            const unsigned short h = f2bf(v);
            hi[j] = h;
            lo[j] = f2bf(v - bf2f(h));
        }
        unsigned short* tb = w1b2 + (size_t)bi * 7168;
        *(us8*)(tb + (size_t)s * 8)         = hi;
        *(us8*)(tb + (size_t)(448 + s) * 8) = lo;
    }
}

// ---------------------------------------------------------------------------
// gating softmax (fp32, proven)
// ---------------------------------------------------------------------------
__global__ __launch_bounds__(128) void gate_kernel(
    const float* __restrict__ x, const float* __restrict__ y,
    const float* __restrict__ wall, float* __restrict__ wgate)
{
    __shared__ float s[D_];
    __shared__ float zv[128];
    __shared__ float red[128];
    const int b = blockIdx.x;
    const int tid = threadIdx.x;

    for (int d = tid; d < D_; d += 128)
        s[d] = x[(size_t)b * D_ + d] + y[(size_t)b * D_ + d];
    __syncthreads();

    float acc = 0.f;
    if (tid < E_)
        for (int d = 0; d < D_; ++d) acc += s[d] * wall[(size_t)d * E_ + tid];
    zv[tid] = (tid < E_) ? acc : -INFINITY;
    red[tid] = zv[tid];
    __syncthreads();
    for (int st = 64; st > 0; st >>= 1) {
        if (tid < st) red[tid] = fmaxf(red[tid], red[tid + st]);
        __syncthreads();
    }
    const float m = red[0];
    __syncthreads();
    const float ev = (tid < E_) ? expf(zv[tid] - m) : 0.f;
    red[tid] = ev;
    __syncthreads();
    for (int st = 64; st > 0; st >>= 1) {
        if (tid < st) red[tid] += red[tid + st];
        __syncthreads();
    }
    if (tid < E_) wgate[(size_t)b * E_ + tid] = ev / red[0];
}

// ---------------------------------------------------------------------------
// main fused kernel: grid (128, 100), 256 threads (4 waves).
// Phase A: split-bf16 MFMA projection.
//   - B: LDS double-buffered (stage kt+1 while computing kt), 1 barrier/kt
//   - A: per-wave frags loaded DIRECTLY global->VGPR, pipelined 1 kt ahead
// Phase B: cos + feat assembly (frozen). Phase C: fp16 MFMA MLP (frozen).
// LDS: 28,672 + 29,696 + 18,560 = 76,928 B -> 2 blocks/CU.
// ---------------------------------------------------------------------------
template<bool USE_PD>
__global__ __launch_bounds__(256) void moe_mfma_kernel(
    const float* __restrict__ tag,
    const unsigned short* __restrict__ ab2,
    const unsigned short* __restrict__ w1b2,
    const float* __restrict__ b1,
    const float* __restrict__ wh,
    const float* __restrict__ hb,
    const float* __restrict__ wo,
    const float* __restrict__ ob,
    const float* __restrict__ wgate,
    float* __restrict__ pd,
    float* __restrict__ out)
{
    __shared__ __align__(16) unsigned short Bw_lds[2][7168];  // 2 x 14 KB (hi|lo)
    __shared__ __align__(16) _Float16 featl[64][232];         // 29,696 B (k-pad 232)
    __shared__ __align__(16) _Float16 swh2[2][20][232];       // 18,560 B (hi|lo wh^T)

    const int tid  = threadIdx.x;
    const int lane = tid & 63, w = tid >> 6;
    const int rb = blockIdx.x, e = blockIdx.y;
    const int b0 = rb * 64;
    const int li = lane & 15, kgq = lane >> 4;

    // zero feat k-pads [202..231]
    for (int k = tid; k < 64 * 30; k += 256) featl[k / 30][202 + k % 30] = (_Float16)0.f;

    // stage wh[e] as split fp16, transposed: swh2[part][h][f] (hides under phase A)
    for (int k = tid; k < 20 * 232; k += 256) {
        const int h = k / 232, f = k - h * 232;
        const float v = (f < F_) ? wh[((size_t)e * F_ + f) * H_ + h] : 0.f;
        const _Float16 vh = (_Float16)v;
        swh2[0][h][f] = vh;
        swh2[1][h][f] = (_Float16)(v - (float)vh);
    }

    f32x4 accx[7], accy[7];
    #pragma unroll
    for (int ni = 0; ni < 7; ++ni) {
        accx[ni] = (f32x4){0.f, 0.f, 0.f, 0.f};
        accy[ni] = (f32x4){0.f, 0.f, 0.f, 0.f};
    }

    // per-lane bases (ushort units) within a tile
    const int a_base = (kgq * 128 + w * 16 + li) * 8;
    const int b_base = (kgq * 112 + li) * 8;

    // A-frag register double-buffer: [parity][xh, xl, yh, yl]
    bf16x8 areg[2][4];
    auto loadA = [&](int kt, int pb) {
        const unsigned short* tb = ab2 + (size_t)(rb * NT + kt) * 8192 + a_base;
        areg[pb][0] = *(const bf16x8*)(tb);          // x hi
        areg[pb][1] = *(const bf16x8*)(tb + 4096);   // x lo
        areg[pb][2] = *(const bf16x8*)(tb + 512);    // y hi
        areg[pb][3] = *(const bf16x8*)(tb + 4608);   // y lo
    };
    auto stageB = [&](int tt, int bb) {
        const unsigned short* bbase = w1b2 + (size_t)(e * NT + tt) * 7168 + lane * 8;
        #pragma unroll
        for (int k = 0; k < 4; ++k) {
            const int i = w + 4 * k;           // wave-uniform, 0..15; 14 used
            if (i < 14) GLOAD16(bbase + i * 512, &Bw_lds[bb][i * 512]);
        }
    };

    // -------- phase A: B-dbuf + A-reg pipeline, 1 barrier per k-tile --------
    stageB(0, 0);
    loadA(0, 0);
    __syncthreads();                            // vmcnt drain -> Bw[0] ready
    #pragma unroll
    for (int kt = 0; kt < NT; ++kt) {
        const int cb = kt & 1, nb = cb ^ 1;
        if (kt < NT - 1) {
            stageB(kt + 1, nb);                 // DMA into other buffer
            loadA(kt + 1, nb);                  // regs for next tile (latency under MFMAs)
        }
        const bf16x8 axh = areg[cb][0];
        const bf16x8 axl = areg[cb][1];
        const bf16x8 ayh = areg[cb][2];
        const bf16x8 ayl = areg[cb][3];
        #pragma unroll
        for (int ni = 0; ni < 7; ++ni) {
            const bf16x8 bh = *(const bf16x8*)(&Bw_lds[cb][b_base + ni * 128]);
            const bf16x8 bl = *(const bf16x8*)(&Bw_lds[cb][b_base + ni * 128 + 3584]);
            accx[ni] = __builtin_amdgcn_mfma_f32_16x16x32_bf16(axh, bh, accx[ni], 0, 0, 0);
            accx[ni] = __builtin_amdgcn_mfma_f32_16x16x32_bf16(axl, bh, accx[ni], 0, 0, 0);
            accx[ni] = __builtin_amdgcn_mfma_f32_16x16x32_bf16(axh, bl, accx[ni], 0, 0, 0);
            accy[ni] = __builtin_amdgcn_mfma_f32_16x16x32_bf16(ayh, bh, accy[ni], 0, 0, 0);
            accy[ni] = __builtin_amdgcn_mfma_f32_16x16x32_bf16(ayl, bh, accy[ni], 0, 0, 0);
            accy[ni] = __builtin_amdgcn_mfma_f32_16x16x32_bf16(ayh, bl, accy[ni], 0, 0, 0);
        }
        __syncthreads();     // waves done with Bw[cb]; Bw[nb] staging landed
    }

    // -------- phase B: bias, feat, cos (frozen) --------
    float pxx[4] = {0, 0, 0, 0}, pyy[4] = {0, 0, 0, 0}, pxy[4] = {0, 0, 0, 0};
    #pragma unroll
    for (int ni = 0; ni < 7; ++ni) {
        const int c = ni * 16 + li;
        if (c < P_) {
            const float bp = b1[(size_t)e * P_ + c];
            #pragma unroll
            for (int j = 0; j < 4; ++j) {
                const float xv = accx[ni][j] + bp;
                const float yv = accy[ni][j] + bp;
                const int r = w * 16 + kgq * 4 + j;   // C-frag row (m89 layout)
                featl[r][1 + c]   = (_Float16)(xv + yv);
                featl[r][101 + c] = (_Float16)fabsf(xv - yv);
                pxx[j] += xv * xv; pyy[j] += yv * yv; pxy[j] += xv * yv;
            }
        }
    }
    #pragma unroll
    for (int j = 0; j < 4; ++j) {
        #pragma unroll
        for (int m = 1; m < 16; m <<= 1) {
            pxx[j] += __shfl_xor(pxx[j], m);
            pyy[j] += __shfl_xor(pyy[j], m);
            pxy[j] += __shfl_xor(pxy[j], m);
        }
    }
    if (li == 0) {
        #pragma unroll
        for (int j = 0; j < 4; ++j) {
            const int r = w * 16 + kgq * 4 + j;
            const float nx = fmaxf(sqrtf(pxx[j]), 1e-8f);
            const float ny = fmaxf(sqrtf(pyy[j]), 1e-8f);
            featl[r][0]   = (_Float16)(pxy[j] / (nx * ny));
            featl[r][201] = (_Float16)tag[b0 + r];
        }
    }
    __syncthreads();

    // -------- phase C: hidden (202->20) via fp16 MFMA + out (20->1) --------
    const int h1 = 16 + li;
    const bool v1 = (h1 < H_);
    const int h1c = v1 ? h1 : (H_ - 1);     // clamped in-bounds row for invalid lanes

    f32x4 acc0 = (f32x4){0.f, 0.f, 0.f, 0.f};
    f32x4 acc1 = (f32x4){0.f, 0.f, 0.f, 0.f};
    #pragma unroll
    for (int kt = 0; kt < 7; ++kt) {
        const int ko = kt * 32 + kgq * 8;
        const f16x8 af  = *(const f16x8*)(&featl[w * 16 + li][ko]);
        const f16x8 b0h = *(const f16x8*)(&swh2[0][li][ko]);
        const f16x8 b0l = *(const f16x8*)(&swh2[1][li][ko]);
        acc0 = __builtin_amdgcn_mfma_f32_16x16x32_f16(af, b0h, acc0, 0, 0, 0);
        acc0 = __builtin_amdgcn_mfma_f32_16x16x32_f16(af, b0l, acc0, 0, 0, 0);
        f16x8 b1h = *(const f16x8*)(&swh2[0][h1c][ko]);
        f16x8 b1l = *(const f16x8*)(&swh2[1][h1c][ko]);
        if (!v1) {                              // zero pad-cols 20..31
            b1h = (f16x8)(_Float16)0.f;
            b1l = (f16x8)(_Float16)0.f;
        }
        acc1 = __builtin_amdgcn_mfma_f32_16x16x32_f16(af, b1h, acc1, 0, 0, 0);
        acc1 = __builtin_amdgcn_mfma_f32_16x16x32_f16(af, b1l, acc1, 0, 0, 0);
    }

    // epilogue: bias + relu + wo, reduce over h (16 lanes), write pd/out
    const float hb0 = hb[(size_t)e * H_ + li];
    const float wo0 = wo[(size_t)e * H_ + li];
    const float hb1 = v1 ? hb[(size_t)e * H_ + h1] : 0.f;
    const float wo1 = v1 ? wo[(size_t)e * H_ + h1] : 0.f;
    #pragma unroll
    for (int j = 0; j < 4; ++j) {
        float t = fmaxf(acc0[j] + hb0, 0.f) * wo0;
        if (v1) t += fmaxf(acc1[j] + hb1, 0.f) * wo1;
        t += __shfl_xor(t, 1);
        t += __shfl_xor(t, 2);
        t += __shfl_xor(t, 4);
        t += __shfl_xor(t, 8);
        if (li == 0) {
            const int r = w * 16 + kgq * 4 + j;   // C-frag row
            const int b = b0 + r;
            const float v = wgate[(size_t)b * E_ + e] * (t + ob[e]);
            if (USE_PD) pd[(size_t)e * B_ + b] = v;
            else        atomicAdd(&out[b], v);
        }
    }
}

// ---------------------------------------------------------------------------
// deterministic reduction over experts (fixed e-ascending order)
// ---------------------------------------------------------------------------
__global__ __launch_bounds__(256) void reduce_kernel(const float* __restrict__ pd,
                                                     float* __restrict__ out)
{
    const int b = blockIdx.x * 256 + threadIdx.x;
    float s = 0.f;
    for (int e = 0; e < E_; ++e) s += pd[(size_t)e * B_ + b];
    out[b] = s;
}

// ---------------------------------------------------------------------------
extern "C" void kernel_launch(void* const* d_in, const int* in_sizes, int n_in,
                              void* d_out, int out_size, void* d_ws, size_t ws_size,
                              hipStream_t stream)
{
    const float* x    = (const float*)d_in[0];
    const float* y    = (const float*)d_in[1];
    const float* tag  = (const float*)d_in[2];
    const float* w1   = (const float*)d_in[3];
    const float* b1   = (const float*)d_in[4];
    const float* wh   = (const float*)d_in[5];
    const float* hb   = (const float*)d_in[6];
    const float* wo   = (const float*)d_in[7];
    const float* ob   = (const float*)d_in[8];
    const float* wall = (const float*)d_in[9];

    float* out = (float*)d_out;
    char* ws = (char*)d_ws;
    float*          wgate = (float*)(ws + WG_OFF);
    unsigned short* ab2   = (unsigned short*)(ws + AB_OFF);
    unsigned short* w1b2  = (unsigned short*)(ws + W1_OFF);
    float*          pd    = (float*)(ws + PD_OFF);

    const bool use_pd = (ws_size >= (size_t)WS_NEEDED);

    prep_xy<<<dim3(128 * NT), dim3(256), 0, stream>>>(x, y, ab2);
    prep_w1<<<dim3(E_ * NT), dim3(256), 0, stream>>>(w1, w1b2);
    gate_kernel<<<dim3(B_), dim3(128), 0, stream>>>(x, y, wall, wgate);

    if (use_pd) {
        moe_mfma_kernel<true><<<dim3(B_ / 64, E_), dim3(256), 0, stream>>>(
            tag, ab2, w1b2, b1, wh, hb, wo, ob, wgate, pd, out);
        reduce_kernel<<<dim3(B_ / 256), dim3(256), 0, stream>>>(pd, out);
    } else {
        hipMemsetAsync(out, 0, (size_t)B_ * sizeof(float), stream);
        moe_mfma_kernel<false><<<dim3(B_ / 64, E_), dim3(256), 0, stream>>>(
            tag, ab2, w1b2, b1, wh, hb, wo, ob, wgate, pd, out);
    }
}

// Round 9
// 490.609 us; speedup vs baseline: 8.9762x; 1.0860x over previous
//
#include <hip/hip_runtime.h>
#include <math.h>

#define B_ 8192
#define E_ 100
#define D_ 300
#define P_ 100
#define H_ 20
#define F_ 202   // 2P+2
#define NT 10    // K steps of 32 (300 padded to 320)
#define NWG 12800
#define CPX (NWG / 8)   // blocks per XCD chunk

typedef __attribute__((ext_vector_type(8))) short bf16x8;
typedef __attribute__((ext_vector_type(8))) _Float16 f16x8;
typedef __attribute__((ext_vector_type(4))) float f32x4;
typedef __attribute__((ext_vector_type(8))) unsigned short us8;

// ---- workspace layout (bytes) ----
#define WG_OFF 0                         // wgate [B][E] f32        (3,276,800)
#define AB_OFF 3276800                   // 128*10*8192 halves      (20,971,520)
#define W1_OFF (AB_OFF + 20971520)       // 100*10*7168 halves      (14,336,000)
#define PD_OFF (W1_OFF + 14336000)       // pd [E][B] f32           (3,276,800)
#define WS_NEEDED (PD_OFF + 3276800)     // 41,861,120 B

__device__ __forceinline__ unsigned short f2bf(float f) {
    unsigned int u = __float_as_uint(f);
    u = (u + 0x7FFF + ((u >> 16) & 1)) >> 16;   // RNE
    return (unsigned short)u;
}
__device__ __forceinline__ float bf2f(unsigned short h) {
    return __uint_as_float(((unsigned int)h) << 16);
}

#define GLOAD16(g, l) \
    __builtin_amdgcn_global_load_lds((const __attribute__((address_space(1))) unsigned int*)(g), \
                                     (__attribute__((address_space(3))) unsigned int*)(l), 16, 0, 0)

// ---------------------------------------------------------------------------
// prep: x,y -> split bf16 A-tiles. tile(rb,t) = [2][4 kg][128 row][8 k] (proven)
// ---------------------------------------------------------------------------
__global__ __launch_bounds__(256) void prep_xy(const float* __restrict__ x,
                                               const float* __restrict__ y,
                                               unsigned short* __restrict__ ab2)
{
    const int bi = blockIdx.x;               // rb*10 + t
    const int rb = bi / NT, t = bi - rb * NT;
    for (int s = threadIdx.x; s < 512; s += 256) {
        const int kg = s >> 7, row = s & 127;
        const float* src = ((row < 64) ? x : y) + (size_t)(rb * 64 + (row & 63)) * D_;
        const int k0 = t * 32 + kg * 8;
        us8 hi, lo;
        #pragma unroll
        for (int j = 0; j < 8; ++j) {
            const int k = k0 + j;
            const float v = (k < D_) ? src[k] : 0.f;
            const unsigned short h = f2bf(v);
            hi[j] = h;
            lo[j] = f2bf(v - bf2f(h));
        }
        unsigned short* tb = ab2 + (size_t)bi * 8192;
        *(us8*)(tb + (size_t)s * 8)         = hi;
        *(us8*)(tb + (size_t)(512 + s) * 8) = lo;
    }
}

// ---------------------------------------------------------------------------
// prep: W1 -> split bf16 B-tiles. tile(e,t) = [2][4 kg][112 p][8 k] (proven)
// ---------------------------------------------------------------------------
__global__ __launch_bounds__(256) void prep_w1(const float* __restrict__ w1,
                                               unsigned short* __restrict__ w1b2)
{
    const int bi = blockIdx.x;               // e*10 + t
    const int e = bi / NT, t = bi - e * NT;
    for (int s = threadIdx.x; s < 448; s += 256) {
        const int kg = s / 112, p = s - kg * 112;
        const int k0 = t * 32 + kg * 8;
        us8 hi, lo;
        #pragma unroll
        for (int j = 0; j < 8; ++j) {
            const int k = k0 + j;
            const float v = (p < P_ && k < D_) ? w1[((size_t)e * D_ + k) * P_ + p] : 0.f;
            const unsigned short h = f2bf(v);
            hi[j] = h;
            lo[j] = f2bf(v - bf2f(h));
        }
        unsigned short* tb = w1b2 + (size_t)bi * 7168;
        *(us8*)(tb + (size_t)s * 8)         = hi;
        *(us8*)(tb + (size_t)(448 + s) * 8) = lo;
    }
}

// ---------------------------------------------------------------------------
// gating softmax (fp32, proven)
// ---------------------------------------------------------------------------
__global__ __launch_bounds__(128) void gate_kernel(
    const float* __restrict__ x, const float* __restrict__ y,
    const float* __restrict__ wall, float* __restrict__ wgate)
{
    __shared__ float s[D_];
    __shared__ float zv[128];
    __shared__ float red[128];
    const int b = blockIdx.x;
    const int tid = threadIdx.x;

    for (int d = tid; d < D_; d += 128)
        s[d] = x[(size_t)b * D_ + d] + y[(size_t)b * D_ + d];
    __syncthreads();

    float acc = 0.f;
    if (tid < E_)
        for (int d = 0; d < D_; ++d) acc += s[d] * wall[(size_t)d * E_ + tid];
    zv[tid] = (tid < E_) ? acc : -INFINITY;
    red[tid] = zv[tid];
    __syncthreads();
    for (int st = 64; st > 0; st >>= 1) {
        if (tid < st) red[tid] = fmaxf(red[tid], red[tid + st]);
        __syncthreads();
    }
    const float m = red[0];
    __syncthreads();
    const float ev = (tid < E_) ? expf(zv[tid] - m) : 0.f;
    red[tid] = ev;
    __syncthreads();
    for (int st = 64; st > 0; st >>= 1) {
        if (tid < st) red[tid] += red[tid + st];
        __syncthreads();
    }
    if (tid < E_) wgate[(size_t)b * E_ + tid] = ev / red[0];
}

// ---------------------------------------------------------------------------
// main fused kernel: 1-D grid 12800 (XCD-swizzled), 256 threads (4 waves).
// Phase A: split-bf16 MFMA projection (B dbuf in LDS, A direct->VGPR pipelined)
// Phase B: cos + feat assembly. Phase C: fp16 MFMA MLP. (numerics frozen = R8)
// LDS union: [ Bw dbuf 28,672 (phase A) | featl 29,696 (B/C) ][ swh2 18,560 ]
//   total 48,256 B -> 3 blocks/CU (12 waves/CU), up from 2.
// ---------------------------------------------------------------------------
template<bool USE_PD>
__global__ __launch_bounds__(256, 3) void moe_mfma_kernel(
    const float* __restrict__ tag,
    const unsigned short* __restrict__ ab2,
    const unsigned short* __restrict__ w1b2,
    const float* __restrict__ b1,
    const float* __restrict__ wh,
    const float* __restrict__ hb,
    const float* __restrict__ wo,
    const float* __restrict__ ob,
    const float* __restrict__ wgate,
    float* __restrict__ pd,
    float* __restrict__ out)
{
    __shared__ __align__(16) char smem[48256];
    // phase A view: B double-buffer (dead after phase A)
    unsigned short (*Bw_lds)[7168] = (unsigned short (*)[7168])smem;       // 2 x 14,336 B
    // phase B/C view: featl overlays the staging region
    _Float16 (*featl)[232] = (_Float16 (*)[232])smem;                      // 29,696 B
    // swh2 lives beyond both staging and featl: no overlap, staged early
    _Float16 (*swh2)[20][232] = (_Float16 (*)[20][232])(smem + 29696);     // 18,560 B

    const int tid  = threadIdx.x;
    const int lane = tid & 63, w = tid >> 6;

    // XCD-aware bijective swizzle: each XCD gets a contiguous expert range
    const int bid = blockIdx.x;
    const int swz = (bid & 7) * CPX + (bid >> 3);
    const int rb = swz & 127, e = swz >> 7;
    const int b0 = rb * 64;
    const int li = lane & 15, kgq = lane >> 4;

    // stage wh[e] as split fp16, transposed: swh2[part][h][f] (hides under phase A)
    for (int k = tid; k < 20 * 232; k += 256) {
        const int h = k / 232, f = k - h * 232;
        const float v = (f < F_) ? wh[((size_t)e * F_ + f) * H_ + h] : 0.f;
        const _Float16 vh = (_Float16)v;
        (*swh2)[h][f] = vh;           // part 0
        swh2[1][h][f] = (_Float16)(v - (float)vh);
    }

    f32x4 accx[7], accy[7];
    #pragma unroll
    for (int ni = 0; ni < 7; ++ni) {
        accx[ni] = (f32x4){0.f, 0.f, 0.f, 0.f};
        accy[ni] = (f32x4){0.f, 0.f, 0.f, 0.f};
    }

    // per-lane bases (ushort units) within a tile
    const int a_base = (kgq * 128 + w * 16 + li) * 8;
    const int b_base = (kgq * 112 + li) * 8;

    // A-frag register double-buffer: [parity][xh, xl, yh, yl]
    bf16x8 areg[2][4];
    auto loadA = [&](int kt, int pb) {
        const unsigned short* tb = ab2 + (size_t)(rb * NT + kt) * 8192 + a_base;
        areg[pb][0] = *(const bf16x8*)(tb);          // x hi
        areg[pb][1] = *(const bf16x8*)(tb + 4096);   // x lo
        areg[pb][2] = *(const bf16x8*)(tb + 512);    // y hi
        areg[pb][3] = *(const bf16x8*)(tb + 4608);   // y lo
    };
    auto stageB = [&](int tt, int bb) {
        const unsigned short* bbase = w1b2 + (size_t)(e * NT + tt) * 7168 + lane * 8;
        #pragma unroll
        for (int k = 0; k < 4; ++k) {
            const int i = w + 4 * k;           // wave-uniform, 0..15; 14 used
            if (i < 14) GLOAD16(bbase + i * 512, &Bw_lds[bb][i * 512]);
        }
    };

    // -------- phase A: B-dbuf + A-reg pipeline, 1 barrier per k-tile --------
    stageB(0, 0);
    loadA(0, 0);
    __syncthreads();                            // vmcnt drain -> Bw[0] ready
    #pragma unroll
    for (int kt = 0; kt < NT; ++kt) {
        const int cb = kt & 1, nb = cb ^ 1;
        if (kt < NT - 1) {
            stageB(kt + 1, nb);                 // DMA into other buffer
            loadA(kt + 1, nb);                  // regs for next tile (latency under MFMAs)
        }
        const bf16x8 axh = areg[cb][0];
        const bf16x8 axl = areg[cb][1];
        const bf16x8 ayh = areg[cb][2];
        const bf16x8 ayl = areg[cb][3];
        #pragma unroll
        for (int ni = 0; ni < 7; ++ni) {
            const bf16x8 bh = *(const bf16x8*)(&Bw_lds[cb][b_base + ni * 128]);
            const bf16x8 bl = *(const bf16x8*)(&Bw_lds[cb][b_base + ni * 128 + 3584]);
            accx[ni] = __builtin_amdgcn_mfma_f32_16x16x32_bf16(axh, bh, accx[ni], 0, 0, 0);
            accx[ni] = __builtin_amdgcn_mfma_f32_16x16x32_bf16(axl, bh, accx[ni], 0, 0, 0);
            accx[ni] = __builtin_amdgcn_mfma_f32_16x16x32_bf16(axh, bl, accx[ni], 0, 0, 0);
            accy[ni] = __builtin_amdgcn_mfma_f32_16x16x32_bf16(ayh, bh, accy[ni], 0, 0, 0);
            accy[ni] = __builtin_amdgcn_mfma_f32_16x16x32_bf16(ayl, bh, accy[ni], 0, 0, 0);
            accy[ni] = __builtin_amdgcn_mfma_f32_16x16x32_bf16(ayh, bl, accy[ni], 0, 0, 0);
        }
        __syncthreads();     // waves done with Bw[cb]; Bw[nb] staging landed
    }

    // -------- staging region dead: featl takes over. zero k-pads [202..231] ---
    for (int k = tid; k < 64 * 30; k += 256) featl[k / 30][202 + k % 30] = (_Float16)0.f;

    // -------- phase B: bias, feat, cos (frozen) --------
    float pxx[4] = {0, 0, 0, 0}, pyy[4] = {0, 0, 0, 0}, pxy[4] = {0, 0, 0, 0};
    #pragma unroll
    for (int ni = 0; ni < 7; ++ni) {
        const int c = ni * 16 + li;
        if (c < P_) {
            const float bp = b1[(size_t)e * P_ + c];
            #pragma unroll
            for (int j = 0; j < 4; ++j) {
                const float xv = accx[ni][j] + bp;
                const float yv = accy[ni][j] + bp;
                const int r = w * 16 + kgq * 4 + j;   // C-frag row (m89 layout)
                featl[r][1 + c]   = (_Float16)(xv + yv);
                featl[r][101 + c] = (_Float16)fabsf(xv - yv);
                pxx[j] += xv * xv; pyy[j] += yv * yv; pxy[j] += xv * yv;
            }
        }
    }
    #pragma unroll
    for (int j = 0; j < 4; ++j) {
        #pragma unroll
        for (int m = 1; m < 16; m <<= 1) {
            pxx[j] += __shfl_xor(pxx[j], m);
            pyy[j] += __shfl_xor(pyy[j], m);
            pxy[j] += __shfl_xor(pxy[j], m);
        }
    }
    if (li == 0) {
        #pragma unroll
        for (int j = 0; j < 4; ++j) {
            const int r = w * 16 + kgq * 4 + j;
            const float nx = fmaxf(sqrtf(pxx[j]), 1e-8f);
            const float ny = fmaxf(sqrtf(pyy[j]), 1e-8f);
            featl[r][0]   = (_Float16)(pxy[j] / (nx * ny));
            featl[r][201] = (_Float16)tag[b0 + r];
        }
    }
    __syncthreads();

    // -------- phase C: hidden (202->20) via fp16 MFMA + out (20->1) --------
    const int h1 = 16 + li;
    const bool v1 = (h1 < H_);
    const int h1c = v1 ? h1 : (H_ - 1);     // clamped in-bounds row for invalid lanes

    f32x4 acc0 = (f32x4){0.f, 0.f, 0.f, 0.f};
    f32x4 acc1 = (f32x4){0.f, 0.f, 0.f, 0.f};
    #pragma unroll
    for (int kt = 0; kt < 7; ++kt) {
        const int ko = kt * 32 + kgq * 8;
        const f16x8 af  = *(const f16x8*)(&featl[w * 16 + li][ko]);
        const f16x8 b0h = *(const f16x8*)(&(*swh2)[li][ko]);
        const f16x8 b0l = *(const f16x8*)(&swh2[1][li][ko]);
        acc0 = __builtin_amdgcn_mfma_f32_16x16x32_f16(af, b0h, acc0, 0, 0, 0);
        acc0 = __builtin_amdgcn_mfma_f32_16x16x32_f16(af, b0l, acc0, 0, 0, 0);
        f16x8 b1h = *(const f16x8*)(&(*swh2)[h1c][ko]);
        f16x8 b1l = *(const f16x8*)(&swh2[1][h1c][ko]);
        if (!v1) {                              // zero pad-cols 20..31
            b1h = (f16x8)(_Float16)0.f;
            b1l = (f16x8)(_Float16)0.f;
        }
        acc1 = __builtin_amdgcn_mfma_f32_16x16x32_f16(af, b1h, acc1, 0, 0, 0);
        acc1 = __builtin_amdgcn_mfma_f32_16x16x32_f16(af, b1l, acc1, 0, 0, 0);
    }

    // epilogue: bias + relu + wo, reduce over h (16 lanes), write pd/out
    const float hb0 = hb[(size_t)e * H_ + li];
    const float wo0 = wo[(size_t)e * H_ + li];
    const float hb1 = v1 ? hb[(size_t)e * H_ + h1] : 0.f;
    const float wo1 = v1 ? wo[(size_t)e * H_ + h1] : 0.f;
    #pragma unroll
    for (int j = 0; j < 4; ++j) {
        float t = fmaxf(acc0[j] + hb0, 0.f) * wo0;
        if (v1) t += fmaxf(acc1[j] + hb1, 0.f) * wo1;
        t += __shfl_xor(t, 1);
        t += __shfl_xor(t, 2);
        t += __shfl_xor(t, 4);
        t += __shfl_xor(t, 8);
        if (li == 0) {
            const int r = w * 16 + kgq * 4 + j;   // C-frag row
            const int b = b0 + r;
            const float v = wgate[(size_t)b * E_ + e] * (t + ob[e]);
            if (USE_PD) pd[(size_t)e * B_ + b] = v;
            else        atomicAdd(&out[b], v);
        }
    }
}

// ---------------------------------------------------------------------------
// deterministic reduction over experts (fixed e-ascending order)
// ---------------------------------------------------------------------------
__global__ __launch_bounds__(256) void reduce_kernel(const float* __restrict__ pd,
                                                     float* __restrict__ out)
{
    const int b = blockIdx.x * 256 + threadIdx.x;
    float s = 0.f;
    for (int e = 0; e < E_; ++e) s += pd[(size_t)e * B_ + b];
    out[b] = s;
}

// ---------------------------------------------------------------------------
extern "C" void kernel_launch(void* const* d_in, const int* in_sizes, int n_in,
                              void* d_out, int out_size, void* d_ws, size_t ws_size,
                              hipStream_t stream)
{
    const float* x    = (const float*)d_in[0];
    const float* y    = (const float*)d_in[1];
    const float* tag  = (const float*)d_in[2];
    const float* w1   = (const float*)d_in[3];
    const float* b1   = (const float*)d_in[4];
    const float* wh   = (const float*)d_in[5];
    const float* hb   = (const float*)d_in[6];
    const float* wo   = (const float*)d_in[7];
    const float* ob   = (const float*)d_in[8];
    const float* wall = (const float*)d_in[9];

    float* out = (float*)d_out;
    char* ws = (char*)d_ws;
    float*          wgate = (float*)(ws + WG_OFF);
    unsigned short* ab2   = (unsigned short*)(ws + AB_OFF);
    unsigned short* w1b2  = (unsigned short*)(ws + W1_OFF);
    float*          pd    = (float*)(ws + PD_OFF);

    const bool use_pd = (ws_size >= (size_t)WS_NEEDED);

    prep_xy<<<dim3(128 * NT), dim3(256), 0, stream>>>(x, y, ab2);
    prep_w1<<<dim3(E_ * NT), dim3(256), 0, stream>>>(w1, w1b2);
    gate_kernel<<<dim3(B_), dim3(128), 0, stream>>>(x, y, wall, wgate);

    if (use_pd) {
        moe_mfma_kernel<true><<<dim3(NWG), dim3(256), 0, stream>>>(
            tag, ab2, w1b2, b1, wh, hb, wo, ob, wgate, pd, out);
        reduce_kernel<<<dim3(B_ / 256), dim3(256), 0, stream>>>(pd, out);
    } else {
        hipMemsetAsync(out, 0, (size_t)B_ * sizeof(float), stream);
        moe_mfma_kernel<false><<<dim3(NWG), dim3(256), 0, stream>>>(
            tag, ab2, w1b2, b1, wh, hb, wo, ob, wgate, pd, out);
    }
}

// Round 10
// 442.949 us; speedup vs baseline: 9.9421x; 1.1076x over previous
//
#include <hip/hip_runtime.h>
#include <math.h>

#define B_ 8192
#define E_ 100
#define D_ 300
#define P_ 100
#define H_ 20
#define F_ 202   // 2P+2
#define NT 10    // K steps of 32 (300 padded to 320)
#define NWG 12800

typedef __attribute__((ext_vector_type(8))) short bf16x8;
typedef __attribute__((ext_vector_type(8))) _Float16 f16x8;
typedef __attribute__((ext_vector_type(4))) float f32x4;
typedef __attribute__((ext_vector_type(8))) unsigned short us8;

// ---- workspace layout (bytes) ----
#define WG_OFF 0                         // wgate [B][E] f32        (3,276,800)
#define AB_OFF 3276800                   // 128*10*8192 halves      (20,971,520)
#define W1_OFF (AB_OFF + 20971520)       // 100*10*7168 halves      (14,336,000)
#define PD_OFF (W1_OFF + 14336000)       // pd [E][B] f32           (3,276,800)
#define WS_NEEDED (PD_OFF + 3276800)     // 41,861,120 B

__device__ __forceinline__ unsigned short f2bf(float f) {
    unsigned int u = __float_as_uint(f);
    u = (u + 0x7FFF + ((u >> 16) & 1)) >> 16;   // RNE
    return (unsigned short)u;
}
__device__ __forceinline__ float bf2f(unsigned short h) {
    return __uint_as_float(((unsigned int)h) << 16);
}

#define GLOAD16(g, l) \
    __builtin_amdgcn_global_load_lds((const __attribute__((address_space(1))) unsigned int*)(g), \
                                     (__attribute__((address_space(3))) unsigned int*)(l), 16, 0, 0)

// ---------------------------------------------------------------------------
// prep: x,y -> split bf16 A-tiles. tile(rb,t) = [2][4 kg][128 row][8 k] (proven)
// ---------------------------------------------------------------------------
__global__ __launch_bounds__(256) void prep_xy(const float* __restrict__ x,
                                               const float* __restrict__ y,
                                               unsigned short* __restrict__ ab2)
{
    const int bi = blockIdx.x;               // rb*10 + t
    const int rb = bi / NT, t = bi - rb * NT;
    for (int s = threadIdx.x; s < 512; s += 256) {
        const int kg = s >> 7, row = s & 127;
        const float* src = ((row < 64) ? x : y) + (size_t)(rb * 64 + (row & 63)) * D_;
        const int k0 = t * 32 + kg * 8;
        us8 hi, lo;
        #pragma unroll
        for (int j = 0; j < 8; ++j) {
            const int k = k0 + j;
            const float v = (k < D_) ? src[k] : 0.f;
            const unsigned short h = f2bf(v);
            hi[j] = h;
            lo[j] = f2bf(v - bf2f(h));
        }
        unsigned short* tb = ab2 + (size_t)bi * 8192;
        *(us8*)(tb + (size_t)s * 8)         = hi;
        *(us8*)(tb + (size_t)(512 + s) * 8) = lo;
    }
}

// ---------------------------------------------------------------------------
// prep: W1 -> split bf16 B-tiles. tile(e,t) = [2][4 kg][112 p][8 k] (proven)
// ---------------------------------------------------------------------------
__global__ __launch_bounds__(256) void prep_w1(const float* __restrict__ w1,
                                               unsigned short* __restrict__ w1b2)
{
    const int bi = blockIdx.x;               // e*10 + t
    const int e = bi / NT, t = bi - e * NT;
    for (int s = threadIdx.x; s < 448; s += 256) {
        const int kg = s / 112, p = s - kg * 112;
        const int k0 = t * 32 + kg * 8;
        us8 hi, lo;
        #pragma unroll
        for (int j = 0; j < 8; ++j) {
            const int k = k0 + j;
            const float v = (p < P_ && k < D_) ? w1[((size_t)e * D_ + k) * P_ + p] : 0.f;
            const unsigned short h = f2bf(v);
            hi[j] = h;
            lo[j] = f2bf(v - bf2f(h));
        }
        unsigned short* tb = w1b2 + (size_t)bi * 7168;
        *(us8*)(tb + (size_t)s * 8)         = hi;
        *(us8*)(tb + (size_t)(448 + s) * 8) = lo;
    }
}

// ---------------------------------------------------------------------------
// gating softmax (fp32, proven)
// ---------------------------------------------------------------------------
__global__ __launch_bounds__(128) void gate_kernel(
    const float* __restrict__ x, const float* __restrict__ y,
    const float* __restrict__ wall, float* __restrict__ wgate)
{
    __shared__ float s[D_];
    __shared__ float zv[128];
    __shared__ float red[128];
    const int b = blockIdx.x;
    const int tid = threadIdx.x;

    for (int d = tid; d < D_; d += 128)
        s[d] = x[(size_t)b * D_ + d] + y[(size_t)b * D_ + d];
    __syncthreads();

    float acc = 0.f;
    if (tid < E_)
        for (int d = 0; d < D_; ++d) acc += s[d] * wall[(size_t)d * E_ + tid];
    zv[tid] = (tid < E_) ? acc : -INFINITY;
    red[tid] = zv[tid];
    __syncthreads();
    for (int st = 64; st > 0; st >>= 1) {
        if (tid < st) red[tid] = fmaxf(red[tid], red[tid + st]);
        __syncthreads();
    }
    const float m = red[0];
    __syncthreads();
    const float ev = (tid < E_) ? expf(zv[tid] - m) : 0.f;
    red[tid] = ev;
    __syncthreads();
    for (int st = 64; st > 0; st >>= 1) {
        if (tid < st) red[tid] += red[tid + st];
        __syncthreads();
    }
    if (tid < E_) wgate[(size_t)b * E_ + tid] = ev / red[0];
}

// ---------------------------------------------------------------------------
// main fused kernel: 1-D grid 12800, 256 threads (4 waves).
// XCD swizzle v2: XCD (bid&7) owns a fixed 16-rb slice across ALL experts ->
// per-XCD L2 working set = A slice 2.6 MB + ~6 staged B experts 0.9 MB < 4 MB.
// (R9's e-range-per-XCD swizzle thrashed L2: A working set 21 MB -> 1.09 GB
//  fabric traffic at 2.4 TB/s == the whole dispatch time.)
// Phase A: split-bf16 MFMA (B dbuf LDS, A direct->VGPR). Phases B/C frozen.
// LDS union 48,256 B -> 3 blocks/CU.
// ---------------------------------------------------------------------------
template<bool USE_PD>
__global__ __launch_bounds__(256, 3) void moe_mfma_kernel(
    const float* __restrict__ tag,
    const unsigned short* __restrict__ ab2,
    const unsigned short* __restrict__ w1b2,
    const float* __restrict__ b1,
    const float* __restrict__ wh,
    const float* __restrict__ hb,
    const float* __restrict__ wo,
    const float* __restrict__ ob,
    const float* __restrict__ wgate,
    float* __restrict__ pd,
    float* __restrict__ out)
{
    __shared__ __align__(16) char smem[48256];
    // phase A view: B double-buffer (dead after phase A)
    unsigned short (*Bw_lds)[7168] = (unsigned short (*)[7168])smem;       // 2 x 14,336 B
    // phase B/C view: featl overlays the staging region
    _Float16 (*featl)[232] = (_Float16 (*)[232])smem;                      // 29,696 B
    // swh2 lives beyond both staging and featl: no overlap, staged early
    _Float16 (*swh2)[20][232] = (_Float16 (*)[20][232])(smem + 29696);     // 18,560 B

    const int tid  = threadIdx.x;
    const int lane = tid & 63, w = tid >> 6;

    // XCD-aware bijective swizzle v2: rb slice per XCD, e advances slowly.
    // bid&7 -> XCD; rb = 16*(bid&7) + ((bid>>3)&15); e = bid>>7.
    const int bid = blockIdx.x;
    const int rb = ((bid & 7) << 4) | ((bid >> 3) & 15);
    const int e  = bid >> 7;
    const int b0 = rb * 64;
    const int li = lane & 15, kgq = lane >> 4;

    // stage wh[e] as split fp16, transposed: swh2[part][h][f] (hides under phase A)
    for (int k = tid; k < 20 * 232; k += 256) {
        const int h = k / 232, f = k - h * 232;
        const float v = (f < F_) ? wh[((size_t)e * F_ + f) * H_ + h] : 0.f;
        const _Float16 vh = (_Float16)v;
        (*swh2)[h][f] = vh;           // part 0
        swh2[1][h][f] = (_Float16)(v - (float)vh);
    }

    f32x4 accx[7], accy[7];
    #pragma unroll
    for (int ni = 0; ni < 7; ++ni) {
        accx[ni] = (f32x4){0.f, 0.f, 0.f, 0.f};
        accy[ni] = (f32x4){0.f, 0.f, 0.f, 0.f};
    }

    // per-lane bases (ushort units) within a tile
    const int a_base = (kgq * 128 + w * 16 + li) * 8;
    const int b_base = (kgq * 112 + li) * 8;

    // A-frag register double-buffer: [parity][xh, xl, yh, yl]
    bf16x8 areg[2][4];
    auto loadA = [&](int kt, int pb) {
        const unsigned short* tb = ab2 + (size_t)(rb * NT + kt) * 8192 + a_base;
        areg[pb][0] = *(const bf16x8*)(tb);          // x hi
        areg[pb][1] = *(const bf16x8*)(tb + 4096);   // x lo
        areg[pb][2] = *(const bf16x8*)(tb + 512);    // y hi
        areg[pb][3] = *(const bf16x8*)(tb + 4608);   // y lo
    };
    auto stageB = [&](int tt, int bb) {
        const unsigned short* bbase = w1b2 + (size_t)(e * NT + tt) * 7168 + lane * 8;
        #pragma unroll
        for (int k = 0; k < 4; ++k) {
            const int i = w + 4 * k;           // wave-uniform, 0..15; 14 used
            if (i < 14) GLOAD16(bbase + i * 512, &Bw_lds[bb][i * 512]);
        }
    };

    // -------- phase A: B-dbuf + A-reg pipeline, 1 barrier per k-tile --------
    stageB(0, 0);
    loadA(0, 0);
    __syncthreads();                            // vmcnt drain -> Bw[0] ready
    #pragma unroll
    for (int kt = 0; kt < NT; ++kt) {
        const int cb = kt & 1, nb = cb ^ 1;
        if (kt < NT - 1) {
            stageB(kt + 1, nb);                 // DMA into other buffer
            loadA(kt + 1, nb);                  // regs for next tile (latency under MFMAs)
        }
        const bf16x8 axh = areg[cb][0];
        const bf16x8 axl = areg[cb][1];
        const bf16x8 ayh = areg[cb][2];
        const bf16x8 ayl = areg[cb][3];
        #pragma unroll
        for (int ni = 0; ni < 7; ++ni) {
            const bf16x8 bh = *(const bf16x8*)(&Bw_lds[cb][b_base + ni * 128]);
            const bf16x8 bl = *(const bf16x8*)(&Bw_lds[cb][b_base + ni * 128 + 3584]);
            accx[ni] = __builtin_amdgcn_mfma_f32_16x16x32_bf16(axh, bh, accx[ni], 0, 0, 0);
            accx[ni] = __builtin_amdgcn_mfma_f32_16x16x32_bf16(axl, bh, accx[ni], 0, 0, 0);
            accx[ni] = __builtin_amdgcn_mfma_f32_16x16x32_bf16(axh, bl, accx[ni], 0, 0, 0);
            accy[ni] = __builtin_amdgcn_mfma_f32_16x16x32_bf16(ayh, bh, accy[ni], 0, 0, 0);
            accy[ni] = __builtin_amdgcn_mfma_f32_16x16x32_bf16(ayl, bh, accy[ni], 0, 0, 0);
            accy[ni] = __builtin_amdgcn_mfma_f32_16x16x32_bf16(ayh, bl, accy[ni], 0, 0, 0);
        }
        __syncthreads();     // waves done with Bw[cb]; Bw[nb] staging landed
    }

    // -------- staging region dead: featl takes over. zero k-pads [202..231] ---
    for (int k = tid; k < 64 * 30; k += 256) featl[k / 30][202 + k % 30] = (_Float16)0.f;

    // -------- phase B: bias, feat, cos (frozen) --------
    float pxx[4] = {0, 0, 0, 0}, pyy[4] = {0, 0, 0, 0}, pxy[4] = {0, 0, 0, 0};
    #pragma unroll
    for (int ni = 0; ni < 7; ++ni) {
        const int c = ni * 16 + li;
        if (c < P_) {
            const float bp = b1[(size_t)e * P_ + c];
            #pragma unroll
            for (int j = 0; j < 4; ++j) {
                const float xv = accx[ni][j] + bp;
                const float yv = accy[ni][j] + bp;
                const int r = w * 16 + kgq * 4 + j;   // C-frag row (m89 layout)
                featl[r][1 + c]   = (_Float16)(xv + yv);
                featl[r][101 + c] = (_Float16)fabsf(xv - yv);
                pxx[j] += xv * xv; pyy[j] += yv * yv; pxy[j] += xv * yv;
            }
        }
    }
    #pragma unroll
    for (int j = 0; j < 4; ++j) {
        #pragma unroll
        for (int m = 1; m < 16; m <<= 1) {
            pxx[j] += __shfl_xor(pxx[j], m);
            pyy[j] += __shfl_xor(pyy[j], m);
            pxy[j] += __shfl_xor(pxy[j], m);
        }
    }
    if (li == 0) {
        #pragma unroll
        for (int j = 0; j < 4; ++j) {
            const int r = w * 16 + kgq * 4 + j;
            const float nx = fmaxf(sqrtf(pxx[j]), 1e-8f);
            const float ny = fmaxf(sqrtf(pyy[j]), 1e-8f);
            featl[r][0]   = (_Float16)(pxy[j] / (nx * ny));
            featl[r][201] = (_Float16)tag[b0 + r];
        }
    }
    __syncthreads();

    // -------- phase C: hidden (202->20) via fp16 MFMA + out (20->1) --------
    const int h1 = 16 + li;
    const bool v1 = (h1 < H_);
    const int h1c = v1 ? h1 : (H_ - 1);     // clamped in-bounds row for invalid lanes

    f32x4 acc0 = (f32x4){0.f, 0.f, 0.f, 0.f};
    f32x4 acc1 = (f32x4){0.f, 0.f, 0.f, 0.f};
    #pragma unroll
    for (int kt = 0; kt < 7; ++kt) {
        const int ko = kt * 32 + kgq * 8;
        const f16x8 af  = *(const f16x8*)(&featl[w * 16 + li][ko]);
        const f16x8 b0h = *(const f16x8*)(&(*swh2)[li][ko]);
        const f16x8 b0l = *(const f16x8*)(&swh2[1][li][ko]);
        acc0 = __builtin_amdgcn_mfma_f32_16x16x32_f16(af, b0h, acc0, 0, 0, 0);
        acc0 = __builtin_amdgcn_mfma_f32_16x16x32_f16(af, b0l, acc0, 0, 0, 0);
        f16x8 b1h = *(const f16x8*)(&(*swh2)[h1c][ko]);
        f16x8 b1l = *(const f16x8*)(&swh2[1][h1c][ko]);
        if (!v1) {                              // zero pad-cols 20..31
            b1h = (f16x8)(_Float16)0.f;
            b1l = (f16x8)(_Float16)0.f;
        }
        acc1 = __builtin_amdgcn_mfma_f32_16x16x32_f16(af, b1h, acc1, 0, 0, 0);
        acc1 = __builtin_amdgcn_mfma_f32_16x16x32_f16(af, b1l, acc1, 0, 0, 0);
    }

    // epilogue: bias + relu + wo, reduce over h (16 lanes), write pd/out
    const float hb0 = hb[(size_t)e * H_ + li];
    const float wo0 = wo[(size_t)e * H_ + li];
    const float hb1 = v1 ? hb[(size_t)e * H_ + h1] : 0.f;
    const float wo1 = v1 ? wo[(size_t)e * H_ + h1] : 0.f;
    #pragma unroll
    for (int j = 0; j < 4; ++j) {
        float t = fmaxf(acc0[j] + hb0, 0.f) * wo0;
        if (v1) t += fmaxf(acc1[j] + hb1, 0.f) * wo1;
        t += __shfl_xor(t, 1);
        t += __shfl_xor(t, 2);
        t += __shfl_xor(t, 4);
        t += __shfl_xor(t, 8);
        if (li == 0) {
            const int r = w * 16 + kgq * 4 + j;   // C-frag row
            const int b = b0 + r;
            const float v = wgate[(size_t)b * E_ + e] * (t + ob[e]);
            if (USE_PD) pd[(size_t)e * B_ + b] = v;
            else        atomicAdd(&out[b], v);
        }
    }
}

// ---------------------------------------------------------------------------
// deterministic reduction over experts (fixed e-ascending order)
// ---------------------------------------------------------------------------
__global__ __launch_bounds__(256) void reduce_kernel(const float* __restrict__ pd,
                                                     float* __restrict__ out)
{
    const int b = blockIdx.x * 256 + threadIdx.x;
    float s = 0.f;
    for (int e = 0; e < E_; ++e) s += pd[(size_t)e * B_ + b];
    out[b] = s;
}

// ---------------------------------------------------------------------------
extern "C" void kernel_launch(void* const* d_in, const int* in_sizes, int n_in,
                              void* d_out, int out_size, void* d_ws, size_t ws_size,
                              hipStream_t stream)
{
    const float* x    = (const float*)d_in[0];
    const float* y    = (const float*)d_in[1];
    const float* tag  = (const float*)d_in[2];
    const float* w1   = (const float*)d_in[3];
    const float* b1   = (const float*)d_in[4];
    const float* wh   = (const float*)d_in[5];
    const float* hb   = (const float*)d_in[6];
    const float* wo   = (const float*)d_in[7];
    const float* ob   = (const float*)d_in[8];
    const float* wall = (const float*)d_in[9];

    float* out = (float*)d_out;
    char* ws = (char*)d_ws;
    float*          wgate = (float*)(ws + WG_OFF);
    unsigned short* ab2   = (unsigned short*)(ws + AB_OFF);
    unsigned short* w1b2  = (unsigned short*)(ws + W1_OFF);
    float*          pd    = (float*)(ws + PD_OFF);

    const bool use_pd = (ws_size >= (size_t)WS_NEEDED);

    prep_xy<<<dim3(128 * NT), dim3(256), 0, stream>>>(x, y, ab2);
    prep_w1<<<dim3(E_ * NT), dim3(256), 0, stream>>>(w1, w1b2);
    gate_kernel<<<dim3(B_), dim3(128), 0, stream>>>(x, y, wall, wgate);

    if (use_pd) {
        moe_mfma_kernel<true><<<dim3(NWG), dim3(256), 0, stream>>>(
            tag, ab2, w1b2, b1, wh, hb, wo, ob, wgate, pd, out);
        reduce_kernel<<<dim3(B_ / 256), dim3(256), 0, stream>>>(pd, out);
    } else {
        hipMemsetAsync(out, 0, (size_t)B_ * sizeof(float), stream);
        moe_mfma_kernel<false><<<dim3(NWG), dim3(256), 0, stream>>>(
            tag, ab2, w1b2, b1, wh, hb, wo, ob, wgate, pd, out);
    }
}